// Round 2
// baseline (475.458 us; speedup 1.0000x reference)
//
#include <hip/hip_runtime.h>

// MoE layer: router top-2 + per-expert SwiGLU FFN + weighted combine + LayerNorm.
// Tokens=4096, D_MODEL=1024, D_FFN=2048, E=8, TOPK=2. fp32 I/O, bf16 MFMA inside.
//
// R1 (this session): eliminate the convert3 weight-conversion pass (288 MB of
// pure streaming overhead). gateup3/down3 now consume fp32 weights directly:
// B-tiles are reg-staged (float4 loads -> v_cvt_pk_bf16_f32 -> swizzled
// ds_write_b128). A-tiles keep global_load_lds (bf16 sources xb / H).
// 5 dispatches: router_a -> build_lists -> gateup3 -> down3 -> combine+LN.
// Fallback path (small ws): round-1 pipeline, unchanged.

#define D_MODEL 1024
#define D_FFN   2048
#define N_EXP   8
#define TOKENS  4096
#define LISTCAP 4096
#define ROWS_PAD 8320

typedef __bf16 bf16x8 __attribute__((ext_vector_type(8)));
typedef float  f32x4  __attribute__((ext_vector_type(4)));

__device__ __forceinline__ ushort f2bf(float f) {
  union { float f; unsigned u; } v; v.f = f;
  unsigned u = v.u;
  u += 0x7fffu + ((u >> 16) & 1u);   // round-to-nearest-even
  return (ushort)(u >> 16);
}
__device__ __forceinline__ float bf2f(ushort h) {
  union { unsigned u; float f; } v; v.u = ((unsigned)h) << 16; return v.f;
}
__device__ __forceinline__ void gl2lds16(const ushort* g, ushort* l) {
  __builtin_amdgcn_global_load_lds(
      (const __attribute__((address_space(1))) unsigned int*)g,
      (__attribute__((address_space(3))) unsigned int*)l, 16, 0, 0);
}
// packed fp32x2 -> bf16x2 (RNE), one VALU instr
__device__ __forceinline__ unsigned cvtpk(float lo, float hi) {
  unsigned r;
  asm("v_cvt_pk_bf16_f32 %0, %1, %2" : "=v"(r) : "v"(lo), "v"(hi));
  return r;
}

// ======================= FAST PATH ==========================================

// Phase A: per-token logits, top-2 softmax, x -> xb (bf16). NO atomics.
// 4 waves/block, one token per wave.
__global__ __launch_bounds__(256) void router_a_kernel(
    const float* __restrict__ x, const float* __restrict__ wr,
    ushort* __restrict__ xb, int* __restrict__ eids, float* __restrict__ wts)
{
  const int token = blockIdx.x * 4 + (threadIdx.x >> 6);
  const int lane  = threadIdx.x & 63;
  const float* xr = x + (size_t)token * D_MODEL + lane * 16;

  float xv[16];
  #pragma unroll
  for (int j = 0; j < 16; ++j) xv[j] = xr[j];

  ushort* xbr = xb + (size_t)token * D_MODEL + lane * 16;
  #pragma unroll
  for (int half = 0; half < 2; ++half) {
    ushort u8[8];
    #pragma unroll
    for (int j = 0; j < 8; ++j) u8[j] = f2bf(xv[half * 8 + j]);
    *(uint4*)(xbr + half * 8) = *(uint4*)u8;
  }

  float logit[N_EXP];
  #pragma unroll
  for (int e = 0; e < N_EXP; ++e) {
    const float* w = wr + e * D_MODEL + lane * 16;
    float p = 0.f;
    #pragma unroll
    for (int j = 0; j < 16; ++j) p += xv[j] * w[j];
    #pragma unroll
    for (int o = 32; o > 0; o >>= 1) p += __shfl_xor(p, o, 64);
    logit[e] = p;
  }

  if (lane == 0) {
    float v0 = -1e30f, v1 = -1e30f; int i0 = 0, i1 = 0;
    #pragma unroll
    for (int e = 0; e < N_EXP; ++e) {
      float v = logit[e];
      if (v > v0)      { v1 = v0; i1 = i0; v0 = v; i0 = e; }
      else if (v > v1) { v1 = v; i1 = e; }
    }
    float t  = expf(v1 - v0);           // stable 2-way softmax
    eids[token] = i0 | (i1 << 8);
    wts[token * 2]     = 1.f / (1.f + t);
    wts[token * 2 + 1] = t   / (1.f + t);
  }
}

// Phase B: one block per expert. Block-wide exclusive scan assigns positions.
// Deterministic, no atomics. Writes tok_list, slots, counts[e].
__global__ __launch_bounds__(1024) void build_lists_kernel(
    const int* __restrict__ eids, int* __restrict__ counts,
    int* __restrict__ tok_list, int* __restrict__ slots)
{
  const int e = blockIdx.x;
  const int t = threadIdx.x;

  int my_k[4];
  int c = 0;
  #pragma unroll
  for (int i = 0; i < 4; ++i) {
    int tok = t + i * 1024;
    int p  = eids[tok];
    int e0 = p & 0xff, e1 = (p >> 8) & 0xff;
    my_k[i] = (e0 == e) ? 0 : (e1 == e) ? 1 : -1;
    c += (my_k[i] >= 0) ? 1 : 0;
  }

  // wave-level inclusive scan of c
  const int wave = t >> 6, lane = t & 63;
  int v = c;
  #pragma unroll
  for (int o = 1; o < 64; o <<= 1) {
    int n = __shfl_up(v, o, 64);
    if (lane >= o) v += n;
  }

  __shared__ int wsum[16];
  __shared__ int wbase[16];
  if (lane == 63) wsum[wave] = v;
  __syncthreads();
  if (t == 0) {
    int s = 0;
    #pragma unroll
    for (int w = 0; w < 16; ++w) { wbase[w] = s; s += wsum[w]; }
    counts[e] = s;
  }
  __syncthreads();

  int pos = wbase[wave] + v - c;   // exclusive base for this thread
  #pragma unroll
  for (int i = 0; i < 4; ++i) {
    int tok = t + i * 1024;
    if (my_k[i] >= 0) {
      tok_list[e * LISTCAP + pos] = tok;
      slots[tok * 2 + my_k[i]] = e * LISTCAP + pos;
      pos++;
    }
  }
}

// Gate+Up grouped GEMM + SwiGLU -> H (bf16).
// 128(M)x64(N) tile, BK=64. A: indirect via tok_list, global_load_lds with
// pre-swizzled source. B: fp32 weights reg-staged -> cvt_pk -> swizzled ds_write.
__global__ __launch_bounds__(256, 3) void gateup3_kernel(
    const ushort* __restrict__ xb, const float* __restrict__ wg,
    const float* __restrict__ wu, const int* __restrict__ counts,
    const int* __restrict__ tok_list, ushort* __restrict__ H)
{
  const int e  = blockIdx.z;
  const int Ne = counts[e];
  const int m0 = blockIdx.y * 128;
  if (m0 >= Ne) return;
  const int n0 = blockIdx.x * 64;

  int rowoff = 0;
  for (int j = 0; j < e; ++j) rowoff += counts[j];

  __shared__ ushort As[128 * 64];
  __shared__ ushort Bg[64 * 64];
  __shared__ ushort Bu[64 * 64];
  __shared__ int tok_s[128];

  const int tid = threadIdx.x;
  if (tid < 128) {
    int i = m0 + tid;
    tok_s[tid] = tok_list[e * LISTCAP + (i < Ne ? i : Ne - 1)];
  }
  __syncthreads();

  const int wave = tid >> 6;
  const int lane = tid & 63;
  const int rsub = lane >> 3;
  const int cchk = lane & 7;
  const int co   = (cchk ^ rsub) << 3;    // pre-swizzled source col for gl2lds

  const ushort* aSrc[4];
  #pragma unroll
  for (int i = 0; i < 4; ++i)
    aSrc[i] = xb + (size_t)tok_s[wave * 32 + i * 8 + rsub] * D_MODEL + co;
  ushort* aD = &As[(wave * 32) * 64];

  // B staging: thread t stages row (t>>2), 16 fp32 cols at (t&3)*16, for g and u.
  const int br  = tid >> 2;           // 0..63  (row within B tile)
  const int bc  = (tid & 3) * 16;     // fp32 col base
  const int c8a = (tid & 3) * 2;      // first 8-col chunk index
  const float* gF = wg + ((size_t)e * D_FFN + n0 + br) * D_MODEL + bc;
  const float* uF = wu + ((size_t)e * D_FFN + n0 + br) * D_MODEL + bc;
  ushort* gW0 = &Bg[br * 64 + (((c8a    ) ^ (br & 7)) << 3)];
  ushort* gW1 = &Bg[br * 64 + (((c8a + 1) ^ (br & 7)) << 3)];
  ushort* uW0 = &Bu[br * 64 + (((c8a    ) ^ (br & 7)) << 3)];
  ushort* uW1 = &Bu[br * 64 + (((c8a + 1) ^ (br & 7)) << 3)];

  const int wm   = (wave >> 1) * 64;
  const int wn   = (wave & 1) * 32;
  const int lrow = lane & 15;
  const int lq   = lane >> 4;

  f32x4 accg[4][2], accu[4][2];
  #pragma unroll
  for (int i = 0; i < 4; ++i)
    #pragma unroll
    for (int j = 0; j < 2; ++j) {
      accg[i][j] = f32x4{0.f, 0.f, 0.f, 0.f};
      accu[i][j] = f32x4{0.f, 0.f, 0.f, 0.f};
    }

  for (int k0 = 0; k0 < D_MODEL; k0 += 64) {
    #pragma unroll
    for (int i = 0; i < 4; ++i) {
      gl2lds16(aSrc[i], aD + i * 8 * 64);
      aSrc[i] += 64;
    }
    // B: 8 float4 loads (g,u), packed convert, 4 swizzled ds_write_b128
    float4 g0 = *(const float4*)(gF);
    float4 g1 = *(const float4*)(gF + 4);
    float4 g2 = *(const float4*)(gF + 8);
    float4 g3 = *(const float4*)(gF + 12);
    float4 u0 = *(const float4*)(uF);
    float4 u1 = *(const float4*)(uF + 4);
    float4 u2 = *(const float4*)(uF + 8);
    float4 u3 = *(const float4*)(uF + 12);
    gF += 64; uF += 64;
    uint4 q;
    q.x = cvtpk(g0.x, g0.y); q.y = cvtpk(g0.z, g0.w);
    q.z = cvtpk(g1.x, g1.y); q.w = cvtpk(g1.z, g1.w);
    *(uint4*)gW0 = q;
    q.x = cvtpk(g2.x, g2.y); q.y = cvtpk(g2.z, g2.w);
    q.z = cvtpk(g3.x, g3.y); q.w = cvtpk(g3.z, g3.w);
    *(uint4*)gW1 = q;
    q.x = cvtpk(u0.x, u0.y); q.y = cvtpk(u0.z, u0.w);
    q.z = cvtpk(u1.x, u1.y); q.w = cvtpk(u1.z, u1.w);
    *(uint4*)uW0 = q;
    q.x = cvtpk(u2.x, u2.y); q.y = cvtpk(u2.z, u2.w);
    q.z = cvtpk(u3.x, u3.y); q.w = cvtpk(u3.z, u3.w);
    *(uint4*)uW1 = q;
    __syncthreads();

    #pragma unroll
    for (int kk = 0; kk < 2; ++kk) {
      const int c = kk * 4 + lq;
      bf16x8 af[4], bgf[2], buf[2];
      #pragma unroll
      for (int mi = 0; mi < 4; ++mi) {
        int r = wm + mi * 16 + lrow;
        af[mi] = *(const bf16x8*)&As[r * 64 + ((c ^ (r & 7)) << 3)];
      }
      #pragma unroll
      for (int ni = 0; ni < 2; ++ni) {
        int r = wn + ni * 16 + lrow;
        int off = r * 64 + ((c ^ (r & 7)) << 3);
        bgf[ni] = *(const bf16x8*)&Bg[off];
        buf[ni] = *(const bf16x8*)&Bu[off];
      }
      #pragma unroll
      for (int mi = 0; mi < 4; ++mi)
        #pragma unroll
        for (int ni = 0; ni < 2; ++ni) {
          accg[mi][ni] = __builtin_amdgcn_mfma_f32_16x16x32_bf16(af[mi], bgf[ni], accg[mi][ni], 0, 0, 0);
          accu[mi][ni] = __builtin_amdgcn_mfma_f32_16x16x32_bf16(af[mi], buf[ni], accu[mi][ni], 0, 0, 0);
        }
    }
    __syncthreads();
  }

  const int rowbase = rowoff + m0;
  #pragma unroll
  for (int mi = 0; mi < 4; ++mi)
    #pragma unroll
    for (int r4 = 0; r4 < 4; ++r4) {
      int m = wm + mi * 16 + lq * 4 + r4;
      if (m0 + m < Ne) {
        ushort* hr = H + (size_t)(rowbase + m) * D_FFN + n0 + wn + lrow;
        #pragma unroll
        for (int ni = 0; ni < 2; ++ni) {
          float g = accg[mi][ni][r4];
          float u = accu[mi][ni][r4];
          float h = g / (1.f + __expf(-g)) * u;
          hr[ni * 16] = f2bf(h);
        }
      }
    }
}

// Down grouped GEMM -> Y rows (bf16, unweighted). 128x128 tile, BK=64.
// A: H (bf16) via gl2lds. B: fp32 w_down reg-staged -> cvt_pk -> swizzled ds_write.
__global__ __launch_bounds__(256, 3) void down3_kernel(
    const ushort* __restrict__ H, const float* __restrict__ wd,
    const int* __restrict__ counts, ushort* __restrict__ Y)
{
  const int e  = blockIdx.z;
  const int Ne = counts[e];
  const int m0 = blockIdx.y * 128;
  if (m0 >= Ne) return;
  const int n0 = blockIdx.x * 128;

  int rowoff = 0;
  for (int j = 0; j < e; ++j) rowoff += counts[j];
  const int rowbase = rowoff + m0;

  __shared__ ushort As[128 * 64];
  __shared__ ushort Bd[128 * 64];

  const int tid  = threadIdx.x;
  const int wave = tid >> 6;
  const int lane = tid & 63;
  const int rsub = lane >> 3;
  const int cchk = lane & 7;
  const int co   = (cchk ^ rsub) << 3;

  const ushort* aS = H + (size_t)(rowbase + wave * 32 + rsub) * D_FFN + co;
  ushort* aD = &As[(wave * 32) * 64];

  // B staging: thread t stages row (t>>1), 32 fp32 cols at (t&1)*32.
  const int br  = tid >> 1;           // 0..127
  const int bc  = (tid & 1) * 32;     // fp32 col base
  const int c8a = (tid & 1) * 4;      // first of 4 8-col chunks
  const float* dF = wd + ((size_t)e * D_MODEL + n0 + br) * D_FFN + bc;
  ushort* dW0 = &Bd[br * 64 + (((c8a    ) ^ (br & 7)) << 3)];
  ushort* dW1 = &Bd[br * 64 + (((c8a + 1) ^ (br & 7)) << 3)];
  ushort* dW2 = &Bd[br * 64 + (((c8a + 2) ^ (br & 7)) << 3)];
  ushort* dW3 = &Bd[br * 64 + (((c8a + 3) ^ (br & 7)) << 3)];

  const int wm   = (wave >> 1) * 64;
  const int wn   = (wave & 1) * 64;
  const int lrow = lane & 15;
  const int lq   = lane >> 4;

  f32x4 acc[4][4];
  #pragma unroll
  for (int i = 0; i < 4; ++i)
    #pragma unroll
    for (int j = 0; j < 4; ++j) acc[i][j] = f32x4{0.f, 0.f, 0.f, 0.f};

  for (int k0 = 0; k0 < D_FFN; k0 += 64) {
    #pragma unroll
    for (int i = 0; i < 4; ++i)
      gl2lds16(aS + (size_t)i * 8 * D_FFN, aD + i * 8 * 64);
    aS += 64;

    float4 d0 = *(const float4*)(dF);
    float4 d1 = *(const float4*)(dF + 4);
    float4 d2 = *(const float4*)(dF + 8);
    float4 d3 = *(const float4*)(dF + 12);
    float4 d4 = *(const float4*)(dF + 16);
    float4 d5 = *(const float4*)(dF + 20);
    float4 d6 = *(const float4*)(dF + 24);
    float4 d7 = *(const float4*)(dF + 28);
    dF += 64;
    uint4 q;
    q.x = cvtpk(d0.x, d0.y); q.y = cvtpk(d0.z, d0.w);
    q.z = cvtpk(d1.x, d1.y); q.w = cvtpk(d1.z, d1.w);
    *(uint4*)dW0 = q;
    q.x = cvtpk(d2.x, d2.y); q.y = cvtpk(d2.z, d2.w);
    q.z = cvtpk(d3.x, d3.y); q.w = cvtpk(d3.z, d3.w);
    *(uint4*)dW1 = q;
    q.x = cvtpk(d4.x, d4.y); q.y = cvtpk(d4.z, d4.w);
    q.z = cvtpk(d5.x, d5.y); q.w = cvtpk(d5.z, d5.w);
    *(uint4*)dW2 = q;
    q.x = cvtpk(d6.x, d6.y); q.y = cvtpk(d6.z, d6.w);
    q.z = cvtpk(d7.x, d7.y); q.w = cvtpk(d7.z, d7.w);
    *(uint4*)dW3 = q;
    __syncthreads();

    #pragma unroll
    for (int kk = 0; kk < 2; ++kk) {
      const int c = kk * 4 + lq;
      bf16x8 af[4], bf[4];
      #pragma unroll
      for (int mi = 0; mi < 4; ++mi) {
        int r = wm + mi * 16 + lrow;
        af[mi] = *(const bf16x8*)&As[r * 64 + ((c ^ (r & 7)) << 3)];
      }
      #pragma unroll
      for (int ni = 0; ni < 4; ++ni) {
        int r = wn + ni * 16 + lrow;
        bf[ni] = *(const bf16x8*)&Bd[r * 64 + ((c ^ (r & 7)) << 3)];
      }
      #pragma unroll
      for (int mi = 0; mi < 4; ++mi)
        #pragma unroll
        for (int ni = 0; ni < 4; ++ni)
          acc[mi][ni] = __builtin_amdgcn_mfma_f32_16x16x32_bf16(af[mi], bf[ni], acc[mi][ni], 0, 0, 0);
    }
    __syncthreads();
  }

  #pragma unroll
  for (int mi = 0; mi < 4; ++mi)
    #pragma unroll
    for (int r4 = 0; r4 < 4; ++r4) {
      int m = wm + mi * 16 + lq * 4 + r4;
      if (m0 + m < Ne) {
        ushort* yr = Y + (size_t)(rowbase + m) * D_MODEL + n0 + wn + lrow;
        #pragma unroll
        for (int ni = 0; ni < 4; ++ni)
          yr[ni * 16] = f2bf(acc[mi][ni][r4]);
      }
    }
}

// Combine the 2 expert rows per token + LayerNorm -> out (fp32).
__global__ __launch_bounds__(256) void combine_ln3_kernel(
    const ushort* __restrict__ Y, const int* __restrict__ slots,
    const float* __restrict__ wts, const int* __restrict__ counts,
    const float* __restrict__ gamma, const float* __restrict__ beta,
    float* __restrict__ out)
{
  const int token = blockIdx.x;
  const int t = threadIdx.x;

  __shared__ int offs_s[N_EXP];
  if (t == 0) {
    int s = 0;
    #pragma unroll
    for (int j = 0; j < N_EXP; ++j) { offs_s[j] = s; s += counts[j]; }
  }
  __syncthreads();

  const int s0 = slots[token * 2], s1 = slots[token * 2 + 1];
  const float w0 = wts[token * 2], w1 = wts[token * 2 + 1];
  const int r0 = offs_s[s0 >> 12] + (s0 & (LISTCAP - 1));
  const int r1 = offs_s[s1 >> 12] + (s1 & (LISTCAP - 1));

  ushort4 a = *(const ushort4*)(Y + (size_t)r0 * D_MODEL + t * 4);
  ushort4 b = *(const ushort4*)(Y + (size_t)r1 * D_MODEL + t * 4);
  float4 v;
  v.x = w0 * bf2f(a.x) + w1 * bf2f(b.x);
  v.y = w0 * bf2f(a.y) + w1 * bf2f(b.y);
  v.z = w0 * bf2f(a.z) + w1 * bf2f(b.z);
  v.w = w0 * bf2f(a.w) + w1 * bf2f(b.w);

  float s = v.x + v.y + v.z + v.w;
  #pragma unroll
  for (int o = 32; o > 0; o >>= 1) s += __shfl_xor(s, o, 64);
  __shared__ float red[4];
  const int wave = t >> 6, lane = t & 63;
  if (lane == 0) red[wave] = s;
  __syncthreads();
  float mean = (red[0] + red[1] + red[2] + red[3]) * (1.f / D_MODEL);

  float dx = v.x - mean, dy = v.y - mean, dz = v.z - mean, dw = v.w - mean;
  float ss = dx * dx + dy * dy + dz * dz + dw * dw;
  #pragma unroll
  for (int o = 32; o > 0; o >>= 1) ss += __shfl_xor(ss, o, 64);
  __syncthreads();
  if (lane == 0) red[wave] = ss;
  __syncthreads();
  float var = (red[0] + red[1] + red[2] + red[3]) * (1.f / D_MODEL);
  float rs  = rsqrtf(var + 1e-5f);

  float4 g = ((const float4*)gamma)[t];
  float4 bb = ((const float4*)beta)[t];
  float4 o4;
  o4.x = dx * rs * g.x + bb.x;
  o4.y = dy * rs * g.y + bb.y;
  o4.z = dz * rs * g.z + bb.z;
  o4.w = dw * rs * g.w + bb.w;
  ((float4*)(out + (size_t)token * D_MODEL))[t] = o4;
}

// ======================= FALLBACK (round-1, known-correct) ==================
__global__ __launch_bounds__(64) void router_kernel(
    const float* __restrict__ x, const float* __restrict__ wr,
    ushort* __restrict__ xb, int* __restrict__ counts,
    int* __restrict__ tok_list, float* __restrict__ wt_list)
{
  const int token = blockIdx.x;
  const int lane  = threadIdx.x;
  const float* xr = x + (size_t)token * D_MODEL;
  float xv[16];
  #pragma unroll
  for (int j = 0; j < 16; ++j) xv[j] = xr[j * 64 + lane];
  ushort* xbr = xb + (size_t)token * D_MODEL;
  #pragma unroll
  for (int j = 0; j < 16; ++j) xbr[j * 64 + lane] = f2bf(xv[j]);
  float logit[N_EXP];
  #pragma unroll
  for (int e = 0; e < N_EXP; ++e) {
    const float* w = wr + e * D_MODEL;
    float p = 0.f;
    #pragma unroll
    for (int j = 0; j < 16; ++j) p += xv[j] * w[j * 64 + lane];
    #pragma unroll
    for (int o = 32; o > 0; o >>= 1) p += __shfl_xor(p, o, 64);
    logit[e] = p;
  }
  if (lane == 0) {
    float v0 = -1e30f, v1 = -1e30f; int i0 = 0, i1 = 0;
    #pragma unroll
    for (int e = 0; e < N_EXP; ++e) {
      float v = logit[e];
      if (v > v0)      { v1 = v0; i1 = i0; v0 = v; i0 = e; }
      else if (v > v1) { v1 = v; i1 = e; }
    }
    float t  = expf(v1 - v0);
    float w0 = 1.f / (1.f + t);
    float w1 = t   / (1.f + t);
    int p0 = atomicAdd(&counts[i0], 1);
    tok_list[i0 * LISTCAP + p0] = token;
    wt_list[i0 * LISTCAP + p0] = w0;
    int p1 = atomicAdd(&counts[i1], 1);
    tok_list[i1 * LISTCAP + p1] = token;
    wt_list[i1 * LISTCAP + p1] = w1;
  }
}

__global__ void prefix_kernel(const int* __restrict__ counts, int* __restrict__ offsets)
{
  if (threadIdx.x == 0 && blockIdx.x == 0) {
    int s = 0;
    for (int e = 0; e < N_EXP; ++e) { offsets[e] = s; s += counts[e]; }
  }
}

__global__ __launch_bounds__(256, 2) void gateup_kernel(
    const ushort* __restrict__ xb, const float* __restrict__ wg,
    const float* __restrict__ wu, const int* __restrict__ counts,
    const int* __restrict__ offsets, const int* __restrict__ tok_list,
    ushort* __restrict__ H)
{
  const int e  = blockIdx.z;
  const int Ne = counts[e];
  const int m0 = blockIdx.y * 128;
  if (m0 >= Ne) return;
  const int n0 = blockIdx.x * 128;
  __shared__ ushort As[128][80];
  __shared__ ushort Bg[128][80];
  __shared__ ushort Bu[128][80];
  __shared__ int tok_s[128];
  const int tid = threadIdx.x;
  if (tid < 128) {
    int i = m0 + tid;
    tok_s[tid] = tok_list[e * LISTCAP + (i < Ne ? i : 0)];
  }
  __syncthreads();
  const int wave = tid >> 6;
  const int lane = tid & 63;
  const int wm   = (wave >> 1) * 64;
  const int wn   = (wave & 1) * 64;
  const int lrow = lane & 15;
  const int lk   = (lane >> 4) * 8;
  f32x4 accg[4][4], accu[4][4];
  #pragma unroll
  for (int i = 0; i < 4; ++i)
    #pragma unroll
    for (int j = 0; j < 4; ++j) {
      accg[i][j] = f32x4{0.f, 0.f, 0.f, 0.f};
      accu[i][j] = f32x4{0.f, 0.f, 0.f, 0.f};
    }
  const size_t wbase = ((size_t)e * D_FFN + n0) * D_MODEL;
  for (int k0 = 0; k0 < D_MODEL; k0 += 64) {
    #pragma unroll
    for (int r = 0; r < 4; ++r) {
      int idx = tid + r * 256;
      int row = idx >> 3;
      int c8  = (idx & 7) * 8;
      const ushort* src = xb + (size_t)tok_s[row] * D_MODEL + k0 + c8;
      *(uint4*)(&As[row][c8]) = *(const uint4*)src;
    }
    #pragma unroll
    for (int r = 0; r < 8; ++r) {
      int idx = tid + r * 256;
      int row = idx >> 4;
      int c4  = (idx & 15) * 4;
      const size_t off = wbase + (size_t)row * D_MODEL + k0 + c4;
      const float4 g = *(const float4*)(wg + off);
      const float4 u = *(const float4*)(wu + off);
      ushort4 gb; gb.x = f2bf(g.x); gb.y = f2bf(g.y); gb.z = f2bf(g.z); gb.w = f2bf(g.w);
      ushort4 ub; ub.x = f2bf(u.x); ub.y = f2bf(u.y); ub.z = f2bf(u.z); ub.w = f2bf(u.w);
      *(ushort4*)(&Bg[row][c4]) = gb;
      *(ushort4*)(&Bu[row][c4]) = ub;
    }
    __syncthreads();
    #pragma unroll
    for (int kk = 0; kk < 64; kk += 32) {
      bf16x8 af[4], bgf[4], buf[4];
      #pragma unroll
      for (int mi = 0; mi < 4; ++mi)
        af[mi] = *(const bf16x8*)(&As[wm + mi * 16 + lrow][kk + lk]);
      #pragma unroll
      for (int ni = 0; ni < 4; ++ni) {
        bgf[ni] = *(const bf16x8*)(&Bg[wn + ni * 16 + lrow][kk + lk]);
        buf[ni] = *(const bf16x8*)(&Bu[wn + ni * 16 + lrow][kk + lk]);
      }
      #pragma unroll
      for (int mi = 0; mi < 4; ++mi)
        #pragma unroll
        for (int ni = 0; ni < 4; ++ni) {
          accg[mi][ni] = __builtin_amdgcn_mfma_f32_16x16x32_bf16(af[mi], bgf[ni], accg[mi][ni], 0, 0, 0);
          accu[mi][ni] = __builtin_amdgcn_mfma_f32_16x16x32_bf16(af[mi], buf[ni], accu[mi][ni], 0, 0, 0);
        }
    }
    __syncthreads();
  }
  const int row_base = offsets[e] + m0;
  #pragma unroll
  for (int mi = 0; mi < 4; ++mi)
    #pragma unroll
    for (int ni = 0; ni < 4; ++ni)
      #pragma unroll
      for (int r4 = 0; r4 < 4; ++r4) {
        int m = wm + mi * 16 + (lane >> 4) * 4 + r4;
        if (m0 + m < Ne) {
          int n = wn + ni * 16 + (lane & 15);
          float g = accg[mi][ni][r4];
          float u = accu[mi][ni][r4];
          float h = g / (1.f + __expf(-g)) * u;
          H[(size_t)(row_base + m) * D_FFN + (n0 + n)] = f2bf(h);
        }
      }
}

__global__ __launch_bounds__(256, 2) void down_kernel(
    const ushort* __restrict__ H, const float* __restrict__ wd,
    const int* __restrict__ counts, const int* __restrict__ offsets,
    const int* __restrict__ tok_list, const float* __restrict__ wt_list,
    float* __restrict__ out)
{
  const int e  = blockIdx.z;
  const int Ne = counts[e];
  const int m0 = blockIdx.y * 128;
  if (m0 >= Ne) return;
  const int n0 = blockIdx.x * 128;
  __shared__ ushort As[128][80];
  __shared__ ushort Bd[128][80];
  __shared__ int   tok_s[128];
  __shared__ float wt_s[128];
  const int tid = threadIdx.x;
  if (tid < 128) {
    int i  = m0 + tid;
    int ok = (i < Ne);
    tok_s[tid] = tok_list[e * LISTCAP + (ok ? i : 0)];
    wt_s[tid]  = ok ? wt_list[e * LISTCAP + i] : 0.f;
  }
  __syncthreads();
  const int wave = tid >> 6;
  const int lane = tid & 63;
  const int wm   = (wave >> 1) * 64;
  const int wn   = (wave & 1) * 64;
  const int lrow = lane & 15;
  const int lk   = (lane >> 4) * 8;
  const int row_base = offsets[e] + m0;
  f32x4 acc[4][4];
  #pragma unroll
  for (int i = 0; i < 4; ++i)
    #pragma unroll
    for (int j = 0; j < 4; ++j) acc[i][j] = f32x4{0.f, 0.f, 0.f, 0.f};
  const size_t wdbase = ((size_t)e * D_MODEL + n0) * D_FFN;
  for (int k0 = 0; k0 < D_FFN; k0 += 64) {
    #pragma unroll
    for (int r = 0; r < 4; ++r) {
      int idx = tid + r * 256;
      int row = idx >> 3;
      int c8  = (idx & 7) * 8;
      const ushort* src = H + (size_t)(row_base + row) * D_FFN + k0 + c8;
      *(uint4*)(&As[row][c8]) = *(const uint4*)src;
    }
    #pragma unroll
    for (int r = 0; r < 8; ++r) {
      int idx = tid + r * 256;
      int row = idx >> 4;
      int c4  = (idx & 15) * 4;
      const float4 d = *(const float4*)(wd + wdbase + (size_t)row * D_FFN + k0 + c4);
      ushort4 db; db.x = f2bf(d.x); db.y = f2bf(d.y); db.z = f2bf(d.z); db.w = f2bf(d.w);
      *(ushort4*)(&Bd[row][c4]) = db;
    }
    __syncthreads();
    #pragma unroll
    for (int kk = 0; kk < 64; kk += 32) {
      bf16x8 af[4], bdf[4];
      #pragma unroll
      for (int mi = 0; mi < 4; ++mi)
        af[mi] = *(const bf16x8*)(&As[wm + mi * 16 + lrow][kk + lk]);
      #pragma unroll
      for (int ni = 0; ni < 4; ++ni)
        bdf[ni] = *(const bf16x8*)(&Bd[wn + ni * 16 + lrow][kk + lk]);
      #pragma unroll
      for (int mi = 0; mi < 4; ++mi)
        #pragma unroll
        for (int ni = 0; ni < 4; ++ni)
          acc[mi][ni] = __builtin_amdgcn_mfma_f32_16x16x32_bf16(af[mi], bdf[ni], acc[mi][ni], 0, 0, 0);
    }
    __syncthreads();
  }
  #pragma unroll
  for (int mi = 0; mi < 4; ++mi)
    #pragma unroll
    for (int ni = 0; ni < 4; ++ni)
      #pragma unroll
      for (int r4 = 0; r4 < 4; ++r4) {
        int m = wm + mi * 16 + (lane >> 4) * 4 + r4;
        if (m0 + m < Ne) {
          int n = wn + ni * 16 + (lane & 15);
          float v = acc[mi][ni][r4] * wt_s[m];
          atomicAdd(&out[(size_t)tok_s[m] * D_MODEL + (n0 + n)], v);
        }
      }
}

__global__ __launch_bounds__(256) void ln_kernel(
    float* __restrict__ out, const float* __restrict__ gamma,
    const float* __restrict__ beta)
{
  const int row = blockIdx.x;
  const int t   = threadIdx.x;
  float* rp = out + (size_t)row * D_MODEL;
  float4 v = ((const float4*)rp)[t];
  float s = v.x + v.y + v.z + v.w;
  #pragma unroll
  for (int o = 32; o > 0; o >>= 1) s += __shfl_xor(s, o, 64);
  __shared__ float red[4];
  const int wave = t >> 6, lane = t & 63;
  if (lane == 0) red[wave] = s;
  __syncthreads();
  float mean = (red[0] + red[1] + red[2] + red[3]) * (1.f / D_MODEL);
  float dx = v.x - mean, dy = v.y - mean, dz = v.z - mean, dw = v.w - mean;
  float ss = dx * dx + dy * dy + dz * dz + dw * dw;
  #pragma unroll
  for (int o = 32; o > 0; o >>= 1) ss += __shfl_xor(ss, o, 64);
  __syncthreads();
  if (lane == 0) red[wave] = ss;
  __syncthreads();
  float var = (red[0] + red[1] + red[2] + red[3]) * (1.f / D_MODEL);
  float rs  = rsqrtf(var + 1e-5f);
  float4 g = ((const float4*)gamma)[t];
  float4 b = ((const float4*)beta)[t];
  float4 o4;
  o4.x = dx * rs * g.x + b.x;
  o4.y = dy * rs * g.y + b.y;
  o4.z = dz * rs * g.z + b.z;
  o4.w = dw * rs * g.w + b.w;
  ((float4*)rp)[t] = o4;
}

// ======================= Launch =============================================
extern "C" void kernel_launch(void* const* d_in, const int* in_sizes, int n_in,
                              void* d_out, int out_size, void* d_ws, size_t ws_size,
                              hipStream_t stream) {
  const float* x        = (const float*)d_in[0];
  const float* w_router = (const float*)d_in[1];
  const float* w_gate   = (const float*)d_in[2];
  const float* w_up     = (const float*)d_in[3];
  const float* w_down   = (const float*)d_in[4];
  const float* ln_gamma = (const float*)d_in[5];
  const float* ln_beta  = (const float*)d_in[6];
  float* out = (float*)d_out;
  char* ws = (char*)d_ws;

  const size_t META = 262144;
  const size_t NEED = META + (size_t)TOKENS * D_MODEL * 2        // xb
                      + (size_t)ROWS_PAD * D_FFN * 2             // H
                      + (size_t)ROWS_PAD * D_MODEL * 2;          // Y  (~60 MB)

  if (ws_size >= NEED) {
    int*   counts   = (int*)ws;
    int*   tok_list = (int*)(ws + 4096);
    int*   slots    = (int*)(ws + 4096 + 131072);
    float* wts      = (float*)(ws + 4096 + 131072 + 32768);
    int*   eids     = (int*)(ws + 4096 + 131072 + 32768 + 32768);
    ushort* xb = (ushort*)(ws + META);
    ushort* H  = xb + (size_t)TOKENS * D_MODEL;
    ushort* Y  = H + (size_t)ROWS_PAD * D_FFN;

    router_a_kernel<<<TOKENS / 4, 256, 0, stream>>>(x, w_router, xb, eids, wts);
    build_lists_kernel<<<N_EXP, 1024, 0, stream>>>(eids, counts, tok_list, slots);
    gateup3_kernel<<<dim3(D_FFN / 64, 32, N_EXP), 256, 0, stream>>>(
        xb, w_gate, w_up, counts, tok_list, H);
    down3_kernel<<<dim3(D_MODEL / 128, 32, N_EXP), 256, 0, stream>>>(
        H, w_down, counts, Y);
    combine_ln3_kernel<<<TOKENS, 256, 0, stream>>>(Y, slots, wts, counts,
                                                   ln_gamma, ln_beta, out);
  } else {
    // round-1 fallback
    int*   counts   = (int*)ws;
    int*   offsets  = counts + 8;
    int*   tok_list = (int*)(ws + 256);
    float* wt_list  = (float*)(ws + 256 + LISTCAP * N_EXP * 4);
    ushort* xb      = (ushort*)(ws + 256 + LISTCAP * N_EXP * 8);
    ushort* H       = xb + (size_t)TOKENS * D_MODEL;

    hipMemsetAsync(counts, 0, 64, stream);
    hipMemsetAsync(out, 0, (size_t)TOKENS * D_MODEL * sizeof(float), stream);
    router_kernel<<<TOKENS, 64, 0, stream>>>(x, w_router, xb, counts, tok_list, wt_list);
    prefix_kernel<<<1, 64, 0, stream>>>(counts, offsets);
    gateup_kernel<<<dim3(D_FFN / 128, 32, N_EXP), 256, 0, stream>>>(
        xb, w_gate, w_up, counts, offsets, tok_list, H);
    down_kernel<<<dim3(D_MODEL / 128, 32, N_EXP), 256, 0, stream>>>(
        H, w_down, counts, offsets, tok_list, wt_list, out);
    ln_kernel<<<TOKENS, 256, 0, stream>>>(out, ln_gamma, ln_beta);
  }
}

// Round 3
// 398.041 us; speedup vs baseline: 1.1945x; 1.1945x over previous
//
#include <hip/hip_runtime.h>

// MoE layer: router top-2 + per-expert SwiGLU FFN + weighted combine + LayerNorm.
// Tokens=4096, D_MODEL=1024, D_FFN=2048, E=8, TOPK=2. fp32 I/O, bf16 MFMA inside.
//
// R2: revert R1 (fp32-direct weights regressed 378->475: weight re-reads across
// m-tiles double at fp32 and sync load->cvt->ds_write chains put HBM latency on
// the critical path; convert3 is an amortizer, not overhead). Keep convert3 +
// bf16 weights + gl2lds. ONE change vs R0: down3 retiled 128x128 -> 128x64
// (512 -> ~1024 working blocks; R1 counters showed down3 occupancy-starved).
//
// Fast path (6 dispatches): router_a -> build_lists -> convert3 -> gateup3
// (128x64) -> down3 (128x64) -> combine+LN. Fallback: round-1 pipeline.

#define D_MODEL 1024
#define D_FFN   2048
#define N_EXP   8
#define TOKENS  4096
#define LISTCAP 4096
#define ROWS_PAD 8320
#define W_ELEM  16777216u   // N_EXP * D_FFN * D_MODEL

typedef __bf16 bf16x8 __attribute__((ext_vector_type(8)));
typedef float  f32x4  __attribute__((ext_vector_type(4)));

__device__ __forceinline__ ushort f2bf(float f) {
  union { float f; unsigned u; } v; v.f = f;
  unsigned u = v.u;
  u += 0x7fffu + ((u >> 16) & 1u);   // round-to-nearest-even
  return (ushort)(u >> 16);
}
__device__ __forceinline__ float bf2f(ushort h) {
  union { unsigned u; float f; } v; v.u = ((unsigned)h) << 16; return v.f;
}
__device__ __forceinline__ void gl2lds16(const ushort* g, ushort* l) {
  __builtin_amdgcn_global_load_lds(
      (const __attribute__((address_space(1))) unsigned int*)g,
      (__attribute__((address_space(3))) unsigned int*)l, 16, 0, 0);
}

// ======================= FAST PATH ==========================================

// Phase A: per-token logits, top-2 softmax, x -> xb (bf16). NO atomics.
__global__ __launch_bounds__(256) void router_a_kernel(
    const float* __restrict__ x, const float* __restrict__ wr,
    ushort* __restrict__ xb, int* __restrict__ eids, float* __restrict__ wts)
{
  const int token = blockIdx.x * 4 + (threadIdx.x >> 6);
  const int lane  = threadIdx.x & 63;
  const float* xr = x + (size_t)token * D_MODEL + lane * 16;

  float xv[16];
  #pragma unroll
  for (int j = 0; j < 16; ++j) xv[j] = xr[j];

  ushort* xbr = xb + (size_t)token * D_MODEL + lane * 16;
  #pragma unroll
  for (int half = 0; half < 2; ++half) {
    ushort u8[8];
    #pragma unroll
    for (int j = 0; j < 8; ++j) u8[j] = f2bf(xv[half * 8 + j]);
    *(uint4*)(xbr + half * 8) = *(uint4*)u8;
  }

  float logit[N_EXP];
  #pragma unroll
  for (int e = 0; e < N_EXP; ++e) {
    const float* w = wr + e * D_MODEL + lane * 16;
    float p = 0.f;
    #pragma unroll
    for (int j = 0; j < 16; ++j) p += xv[j] * w[j];
    #pragma unroll
    for (int o = 32; o > 0; o >>= 1) p += __shfl_xor(p, o, 64);
    logit[e] = p;
  }

  if (lane == 0) {
    float v0 = -1e30f, v1 = -1e30f; int i0 = 0, i1 = 0;
    #pragma unroll
    for (int e = 0; e < N_EXP; ++e) {
      float v = logit[e];
      if (v > v0)      { v1 = v0; i1 = i0; v0 = v; i0 = e; }
      else if (v > v1) { v1 = v; i1 = e; }
    }
    float t  = expf(v1 - v0);           // stable 2-way softmax
    eids[token] = i0 | (i1 << 8);
    wts[token * 2]     = 1.f / (1.f + t);
    wts[token * 2 + 1] = t   / (1.f + t);
  }
}

// Phase B: one block per expert. Block-wide exclusive scan assigns positions.
__global__ __launch_bounds__(1024) void build_lists_kernel(
    const int* __restrict__ eids, int* __restrict__ counts,
    int* __restrict__ tok_list, int* __restrict__ slots)
{
  const int e = blockIdx.x;
  const int t = threadIdx.x;

  int my_k[4];
  int c = 0;
  #pragma unroll
  for (int i = 0; i < 4; ++i) {
    int tok = t + i * 1024;
    int p  = eids[tok];
    int e0 = p & 0xff, e1 = (p >> 8) & 0xff;
    my_k[i] = (e0 == e) ? 0 : (e1 == e) ? 1 : -1;
    c += (my_k[i] >= 0) ? 1 : 0;
  }

  const int wave = t >> 6, lane = t & 63;
  int v = c;
  #pragma unroll
  for (int o = 1; o < 64; o <<= 1) {
    int n = __shfl_up(v, o, 64);
    if (lane >= o) v += n;
  }

  __shared__ int wsum[16];
  __shared__ int wbase[16];
  if (lane == 63) wsum[wave] = v;
  __syncthreads();
  if (t == 0) {
    int s = 0;
    #pragma unroll
    for (int w = 0; w < 16; ++w) { wbase[w] = s; s += wsum[w]; }
    counts[e] = s;
  }
  __syncthreads();

  int pos = wbase[wave] + v - c;   // exclusive base for this thread
  #pragma unroll
  for (int i = 0; i < 4; ++i) {
    int tok = t + i * 1024;
    if (my_k[i] >= 0) {
      tok_list[e * LISTCAP + pos] = tok;
      slots[tok * 2 + my_k[i]] = e * LISTCAP + pos;
      pos++;
    }
  }
}

// Fused fp32 -> bf16 conversion of all three weight tensors (one dispatch).
__global__ __launch_bounds__(256) void convert3_kernel(
    const float* __restrict__ wg, const float* __restrict__ wu,
    const float* __restrict__ wd, ushort* __restrict__ dstBase)
{
  const int bid = blockIdx.x;
  const int arr = bid >> 13;              // 8192 blocks per array
  const float* src = (arr == 0) ? wg : (arr == 1) ? wu : wd;
  ushort* dst = dstBase + (size_t)arr * W_ELEM;
  const size_t base = (((size_t)(bid & 8191)) * 256 + threadIdx.x) * 8;
  float4 a = *(const float4*)(src + base);
  float4 b = *(const float4*)(src + base + 4);
  ushort u8[8] = {f2bf(a.x), f2bf(a.y), f2bf(a.z), f2bf(a.w),
                  f2bf(b.x), f2bf(b.y), f2bf(b.z), f2bf(b.w)};
  *(uint4*)(dst + base) = *(uint4*)u8;
}

// Gate+Up grouped GEMM + SwiGLU -> H (bf16).
// 128(M)x64(N) tile, BK=64, indirect A via tok_list, global_load_lds + XOR swizzle.
__global__ __launch_bounds__(256, 3) void gateup3_kernel(
    const ushort* __restrict__ xb, const ushort* __restrict__ WgB,
    const ushort* __restrict__ WuB, const int* __restrict__ counts,
    const int* __restrict__ tok_list, ushort* __restrict__ H)
{
  const int e  = blockIdx.z;
  const int Ne = counts[e];
  const int m0 = blockIdx.y * 128;
  if (m0 >= Ne) return;
  const int n0 = blockIdx.x * 64;

  int rowoff = 0;
  for (int j = 0; j < e; ++j) rowoff += counts[j];

  __shared__ ushort As[128 * 64];
  __shared__ ushort Bg[64 * 64];
  __shared__ ushort Bu[64 * 64];
  __shared__ int tok_s[128];

  const int tid = threadIdx.x;
  if (tid < 128) {
    int i = m0 + tid;
    tok_s[tid] = tok_list[e * LISTCAP + (i < Ne ? i : Ne - 1)];
  }
  __syncthreads();

  const int wave = tid >> 6;
  const int lane = tid & 63;
  const int rsub = lane >> 3;
  const int cchk = lane & 7;
  const int co   = (cchk ^ rsub) << 3;    // r&7 == rsub for all staged rows

  const ushort* aSrc[4];
  #pragma unroll
  for (int i = 0; i < 4; ++i)
    aSrc[i] = xb + (size_t)tok_s[wave * 32 + i * 8 + rsub] * D_MODEL + co;
  const ushort* gS = WgB + ((size_t)e * D_FFN + n0 + wave * 16 + rsub) * D_MODEL + co;
  const ushort* uS = WuB + ((size_t)e * D_FFN + n0 + wave * 16 + rsub) * D_MODEL + co;
  ushort* aD = &As[(wave * 32) * 64];
  ushort* gD = &Bg[(wave * 16) * 64];
  ushort* uD = &Bu[(wave * 16) * 64];

  const int wm   = (wave >> 1) * 64;
  const int wn   = (wave & 1) * 32;
  const int lrow = lane & 15;
  const int lq   = lane >> 4;

  f32x4 accg[4][2], accu[4][2];
  #pragma unroll
  for (int i = 0; i < 4; ++i)
    #pragma unroll
    for (int j = 0; j < 2; ++j) {
      accg[i][j] = f32x4{0.f, 0.f, 0.f, 0.f};
      accu[i][j] = f32x4{0.f, 0.f, 0.f, 0.f};
    }

  for (int k0 = 0; k0 < D_MODEL; k0 += 64) {
    #pragma unroll
    for (int i = 0; i < 4; ++i) {
      gl2lds16(aSrc[i], aD + i * 8 * 64);
      aSrc[i] += 64;
    }
    #pragma unroll
    for (int i = 0; i < 2; ++i) {
      gl2lds16(gS + (size_t)i * 8 * D_MODEL, gD + i * 8 * 64);
      gl2lds16(uS + (size_t)i * 8 * D_MODEL, uD + i * 8 * 64);
    }
    gS += 64; uS += 64;
    __syncthreads();

    #pragma unroll
    for (int kk = 0; kk < 2; ++kk) {
      const int c = kk * 4 + lq;
      bf16x8 af[4], bgf[2], buf[2];
      #pragma unroll
      for (int mi = 0; mi < 4; ++mi) {
        int r = wm + mi * 16 + lrow;
        af[mi] = *(const bf16x8*)&As[r * 64 + ((c ^ (r & 7)) << 3)];
      }
      #pragma unroll
      for (int ni = 0; ni < 2; ++ni) {
        int r = wn + ni * 16 + lrow;
        int off = r * 64 + ((c ^ (r & 7)) << 3);
        bgf[ni] = *(const bf16x8*)&Bg[off];
        buf[ni] = *(const bf16x8*)&Bu[off];
      }
      #pragma unroll
      for (int mi = 0; mi < 4; ++mi)
        #pragma unroll
        for (int ni = 0; ni < 2; ++ni) {
          accg[mi][ni] = __builtin_amdgcn_mfma_f32_16x16x32_bf16(af[mi], bgf[ni], accg[mi][ni], 0, 0, 0);
          accu[mi][ni] = __builtin_amdgcn_mfma_f32_16x16x32_bf16(af[mi], buf[ni], accu[mi][ni], 0, 0, 0);
        }
    }
    __syncthreads();
  }

  const int rowbase = rowoff + m0;
  #pragma unroll
  for (int mi = 0; mi < 4; ++mi)
    #pragma unroll
    for (int r4 = 0; r4 < 4; ++r4) {
      int m = wm + mi * 16 + lq * 4 + r4;
      if (m0 + m < Ne) {
        ushort* hr = H + (size_t)(rowbase + m) * D_FFN + n0 + wn + lrow;
        #pragma unroll
        for (int ni = 0; ni < 2; ++ni) {
          float g = accg[mi][ni][r4];
          float u = accu[mi][ni][r4];
          float h = g / (1.f + __expf(-g)) * u;
          hr[ni * 16] = f2bf(h);
        }
      }
    }
}

// Down grouped GEMM -> Y rows (bf16, unweighted).
// R2: retiled 128(M)x64(N), BK=64 -> ~1024 working blocks (was 512 at 128x128,
// which under-filled 256 CUs; R1 counters: occupancy 15%). LDS 24.5 KB.
__global__ __launch_bounds__(256, 4) void down3_kernel(
    const ushort* __restrict__ H, const ushort* __restrict__ WdB,
    const int* __restrict__ counts, ushort* __restrict__ Y)
{
  const int e  = blockIdx.z;
  const int Ne = counts[e];
  const int m0 = blockIdx.y * 128;
  if (m0 >= Ne) return;
  const int n0 = blockIdx.x * 64;

  int rowoff = 0;
  for (int j = 0; j < e; ++j) rowoff += counts[j];
  const int rowbase = rowoff + m0;

  __shared__ ushort As[128 * 64];
  __shared__ ushort Bd[64 * 64];

  const int tid  = threadIdx.x;
  const int wave = tid >> 6;
  const int lane = tid & 63;
  const int rsub = lane >> 3;
  const int cchk = lane & 7;
  const int co   = (cchk ^ rsub) << 3;

  const ushort* aS = H   + (size_t)(rowbase + wave * 32 + rsub) * D_FFN + co;
  const ushort* bS = WdB + ((size_t)e * D_MODEL + n0 + wave * 16 + rsub) * D_FFN + co;
  ushort* aD = &As[(wave * 32) * 64];
  ushort* bD = &Bd[(wave * 16) * 64];

  const int wm   = (wave >> 1) * 64;
  const int wn   = (wave & 1) * 32;
  const int lrow = lane & 15;
  const int lq   = lane >> 4;

  f32x4 acc[4][2];
  #pragma unroll
  for (int i = 0; i < 4; ++i)
    #pragma unroll
    for (int j = 0; j < 2; ++j) acc[i][j] = f32x4{0.f, 0.f, 0.f, 0.f};

  for (int k0 = 0; k0 < D_FFN; k0 += 64) {
    #pragma unroll
    for (int i = 0; i < 4; ++i)
      gl2lds16(aS + (size_t)i * 8 * D_FFN, aD + i * 8 * 64);
    #pragma unroll
    for (int i = 0; i < 2; ++i)
      gl2lds16(bS + (size_t)i * 8 * D_FFN, bD + i * 8 * 64);
    aS += 64; bS += 64;
    __syncthreads();

    #pragma unroll
    for (int kk = 0; kk < 2; ++kk) {
      const int c = kk * 4 + lq;
      bf16x8 af[4], bf[2];
      #pragma unroll
      for (int mi = 0; mi < 4; ++mi) {
        int r = wm + mi * 16 + lrow;
        af[mi] = *(const bf16x8*)&As[r * 64 + ((c ^ (r & 7)) << 3)];
      }
      #pragma unroll
      for (int ni = 0; ni < 2; ++ni) {
        int r = wn + ni * 16 + lrow;
        bf[ni] = *(const bf16x8*)&Bd[r * 64 + ((c ^ (r & 7)) << 3)];
      }
      #pragma unroll
      for (int mi = 0; mi < 4; ++mi)
        #pragma unroll
        for (int ni = 0; ni < 2; ++ni)
          acc[mi][ni] = __builtin_amdgcn_mfma_f32_16x16x32_bf16(af[mi], bf[ni], acc[mi][ni], 0, 0, 0);
    }
    __syncthreads();
  }

  #pragma unroll
  for (int mi = 0; mi < 4; ++mi)
    #pragma unroll
    for (int r4 = 0; r4 < 4; ++r4) {
      int m = wm + mi * 16 + lq * 4 + r4;
      if (m0 + m < Ne) {
        ushort* yr = Y + (size_t)(rowbase + m) * D_MODEL + n0 + wn + lrow;
        #pragma unroll
        for (int ni = 0; ni < 2; ++ni)
          yr[ni * 16] = f2bf(acc[mi][ni][r4]);
      }
    }
}

// Combine the 2 expert rows per token + LayerNorm -> out (fp32).
__global__ __launch_bounds__(256) void combine_ln3_kernel(
    const ushort* __restrict__ Y, const int* __restrict__ slots,
    const float* __restrict__ wts, const int* __restrict__ counts,
    const float* __restrict__ gamma, const float* __restrict__ beta,
    float* __restrict__ out)
{
  const int token = blockIdx.x;
  const int t = threadIdx.x;

  __shared__ int offs_s[N_EXP];
  if (t == 0) {
    int s = 0;
    #pragma unroll
    for (int j = 0; j < N_EXP; ++j) { offs_s[j] = s; s += counts[j]; }
  }
  __syncthreads();

  const int s0 = slots[token * 2], s1 = slots[token * 2 + 1];
  const float w0 = wts[token * 2], w1 = wts[token * 2 + 1];
  const int r0 = offs_s[s0 >> 12] + (s0 & (LISTCAP - 1));
  const int r1 = offs_s[s1 >> 12] + (s1 & (LISTCAP - 1));

  ushort4 a = *(const ushort4*)(Y + (size_t)r0 * D_MODEL + t * 4);
  ushort4 b = *(const ushort4*)(Y + (size_t)r1 * D_MODEL + t * 4);
  float4 v;
  v.x = w0 * bf2f(a.x) + w1 * bf2f(b.x);
  v.y = w0 * bf2f(a.y) + w1 * bf2f(b.y);
  v.z = w0 * bf2f(a.z) + w1 * bf2f(b.z);
  v.w = w0 * bf2f(a.w) + w1 * bf2f(b.w);

  float s = v.x + v.y + v.z + v.w;
  #pragma unroll
  for (int o = 32; o > 0; o >>= 1) s += __shfl_xor(s, o, 64);
  __shared__ float red[4];
  const int wave = t >> 6, lane = t & 63;
  if (lane == 0) red[wave] = s;
  __syncthreads();
  float mean = (red[0] + red[1] + red[2] + red[3]) * (1.f / D_MODEL);

  float dx = v.x - mean, dy = v.y - mean, dz = v.z - mean, dw = v.w - mean;
  float ss = dx * dx + dy * dy + dz * dz + dw * dw;
  #pragma unroll
  for (int o = 32; o > 0; o >>= 1) ss += __shfl_xor(ss, o, 64);
  __syncthreads();
  if (lane == 0) red[wave] = ss;
  __syncthreads();
  float var = (red[0] + red[1] + red[2] + red[3]) * (1.f / D_MODEL);
  float rs  = rsqrtf(var + 1e-5f);

  float4 g = ((const float4*)gamma)[t];
  float4 bb = ((const float4*)beta)[t];
  float4 o4;
  o4.x = dx * rs * g.x + bb.x;
  o4.y = dy * rs * g.y + bb.y;
  o4.z = dz * rs * g.z + bb.z;
  o4.w = dw * rs * g.w + bb.w;
  ((float4*)(out + (size_t)token * D_MODEL))[t] = o4;
}

// ======================= FALLBACK (round-1, known-correct) ==================
__global__ __launch_bounds__(64) void router_kernel(
    const float* __restrict__ x, const float* __restrict__ wr,
    ushort* __restrict__ xb, int* __restrict__ counts,
    int* __restrict__ tok_list, float* __restrict__ wt_list)
{
  const int token = blockIdx.x;
  const int lane  = threadIdx.x;
  const float* xr = x + (size_t)token * D_MODEL;
  float xv[16];
  #pragma unroll
  for (int j = 0; j < 16; ++j) xv[j] = xr[j * 64 + lane];
  ushort* xbr = xb + (size_t)token * D_MODEL;
  #pragma unroll
  for (int j = 0; j < 16; ++j) xbr[j * 64 + lane] = f2bf(xv[j]);
  float logit[N_EXP];
  #pragma unroll
  for (int e = 0; e < N_EXP; ++e) {
    const float* w = wr + e * D_MODEL;
    float p = 0.f;
    #pragma unroll
    for (int j = 0; j < 16; ++j) p += xv[j] * w[j * 64 + lane];
    #pragma unroll
    for (int o = 32; o > 0; o >>= 1) p += __shfl_xor(p, o, 64);
    logit[e] = p;
  }
  if (lane == 0) {
    float v0 = -1e30f, v1 = -1e30f; int i0 = 0, i1 = 0;
    #pragma unroll
    for (int e = 0; e < N_EXP; ++e) {
      float v = logit[e];
      if (v > v0)      { v1 = v0; i1 = i0; v0 = v; i0 = e; }
      else if (v > v1) { v1 = v; i1 = e; }
    }
    float t  = expf(v1 - v0);
    float w0 = 1.f / (1.f + t);
    float w1 = t   / (1.f + t);
    int p0 = atomicAdd(&counts[i0], 1);
    tok_list[i0 * LISTCAP + p0] = token;
    wt_list[i0 * LISTCAP + p0] = w0;
    int p1 = atomicAdd(&counts[i1], 1);
    tok_list[i1 * LISTCAP + p1] = token;
    wt_list[i1 * LISTCAP + p1] = w1;
  }
}

__global__ void prefix_kernel(const int* __restrict__ counts, int* __restrict__ offsets)
{
  if (threadIdx.x == 0 && blockIdx.x == 0) {
    int s = 0;
    for (int e = 0; e < N_EXP; ++e) { offsets[e] = s; s += counts[e]; }
  }
}

__global__ __launch_bounds__(256, 2) void gateup_kernel(
    const ushort* __restrict__ xb, const float* __restrict__ wg,
    const float* __restrict__ wu, const int* __restrict__ counts,
    const int* __restrict__ offsets, const int* __restrict__ tok_list,
    ushort* __restrict__ H)
{
  const int e  = blockIdx.z;
  const int Ne = counts[e];
  const int m0 = blockIdx.y * 128;
  if (m0 >= Ne) return;
  const int n0 = blockIdx.x * 128;
  __shared__ ushort As[128][80];
  __shared__ ushort Bg[128][80];
  __shared__ ushort Bu[128][80];
  __shared__ int tok_s[128];
  const int tid = threadIdx.x;
  if (tid < 128) {
    int i = m0 + tid;
    tok_s[tid] = tok_list[e * LISTCAP + (i < Ne ? i : 0)];
  }
  __syncthreads();
  const int wave = tid >> 6;
  const int lane = tid & 63;
  const int wm   = (wave >> 1) * 64;
  const int wn   = (wave & 1) * 64;
  const int lrow = lane & 15;
  const int lk   = (lane >> 4) * 8;
  f32x4 accg[4][4], accu[4][4];
  #pragma unroll
  for (int i = 0; i < 4; ++i)
    #pragma unroll
    for (int j = 0; j < 4; ++j) {
      accg[i][j] = f32x4{0.f, 0.f, 0.f, 0.f};
      accu[i][j] = f32x4{0.f, 0.f, 0.f, 0.f};
    }
  const size_t wbase = ((size_t)e * D_FFN + n0) * D_MODEL;
  for (int k0 = 0; k0 < D_MODEL; k0 += 64) {
    #pragma unroll
    for (int r = 0; r < 4; ++r) {
      int idx = tid + r * 256;
      int row = idx >> 3;
      int c8  = (idx & 7) * 8;
      const ushort* src = xb + (size_t)tok_s[row] * D_MODEL + k0 + c8;
      *(uint4*)(&As[row][c8]) = *(const uint4*)src;
    }
    #pragma unroll
    for (int r = 0; r < 8; ++r) {
      int idx = tid + r * 256;
      int row = idx >> 4;
      int c4  = (idx & 15) * 4;
      const size_t off = wbase + (size_t)row * D_MODEL + k0 + c4;
      const float4 g = *(const float4*)(wg + off);
      const float4 u = *(const float4*)(wu + off);
      ushort4 gb; gb.x = f2bf(g.x); gb.y = f2bf(g.y); gb.z = f2bf(g.z); gb.w = f2bf(g.w);
      ushort4 ub; ub.x = f2bf(u.x); ub.y = f2bf(u.y); ub.z = f2bf(u.z); ub.w = f2bf(u.w);
      *(ushort4*)(&Bg[row][c4]) = gb;
      *(ushort4*)(&Bu[row][c4]) = ub;
    }
    __syncthreads();
    #pragma unroll
    for (int kk = 0; kk < 64; kk += 32) {
      bf16x8 af[4], bgf[4], buf[4];
      #pragma unroll
      for (int mi = 0; mi < 4; ++mi)
        af[mi] = *(const bf16x8*)(&As[wm + mi * 16 + lrow][kk + lk]);
      #pragma unroll
      for (int ni = 0; ni < 4; ++ni) {
        bgf[ni] = *(const bf16x8*)(&Bg[wn + ni * 16 + lrow][kk + lk]);
        buf[ni] = *(const bf16x8*)(&Bu[wn + ni * 16 + lrow][kk + lk]);
      }
      #pragma unroll
      for (int mi = 0; mi < 4; ++mi)
        #pragma unroll
        for (int ni = 0; ni < 4; ++ni) {
          accg[mi][ni] = __builtin_amdgcn_mfma_f32_16x16x32_bf16(af[mi], bgf[ni], accg[mi][ni], 0, 0, 0);
          accu[mi][ni] = __builtin_amdgcn_mfma_f32_16x16x32_bf16(af[mi], buf[ni], accu[mi][ni], 0, 0, 0);
        }
    }
    __syncthreads();
  }
  const int row_base = offsets[e] + m0;
  #pragma unroll
  for (int mi = 0; mi < 4; ++mi)
    #pragma unroll
    for (int ni = 0; ni < 4; ++ni)
      #pragma unroll
      for (int r4 = 0; r4 < 4; ++r4) {
        int m = wm + mi * 16 + (lane >> 4) * 4 + r4;
        if (m0 + m < Ne) {
          int n = wn + ni * 16 + (lane & 15);
          float g = accg[mi][ni][r4];
          float u = accu[mi][ni][r4];
          float h = g / (1.f + __expf(-g)) * u;
          H[(size_t)(row_base + m) * D_FFN + (n0 + n)] = f2bf(h);
        }
      }
}

__global__ __launch_bounds__(256, 2) void down_kernel(
    const ushort* __restrict__ H, const float* __restrict__ wd,
    const int* __restrict__ counts, const int* __restrict__ offsets,
    const int* __restrict__ tok_list, const float* __restrict__ wt_list,
    float* __restrict__ out)
{
  const int e  = blockIdx.z;
  const int Ne = counts[e];
  const int m0 = blockIdx.y * 128;
  if (m0 >= Ne) return;
  const int n0 = blockIdx.x * 128;
  __shared__ ushort As[128][80];
  __shared__ ushort Bd[128][80];
  __shared__ int   tok_s[128];
  __shared__ float wt_s[128];
  const int tid = threadIdx.x;
  if (tid < 128) {
    int i  = m0 + tid;
    int ok = (i < Ne);
    tok_s[tid] = tok_list[e * LISTCAP + (ok ? i : 0)];
    wt_s[tid]  = ok ? wt_list[e * LISTCAP + i] : 0.f;
  }
  __syncthreads();
  const int wave = tid >> 6;
  const int lane = tid & 63;
  const int wm   = (wave >> 1) * 64;
  const int wn   = (wave & 1) * 64;
  const int lrow = lane & 15;
  const int lk   = (lane >> 4) * 8;
  const int row_base = offsets[e] + m0;
  f32x4 acc[4][4];
  #pragma unroll
  for (int i = 0; i < 4; ++i)
    #pragma unroll
    for (int j = 0; j < 4; ++j) acc[i][j] = f32x4{0.f, 0.f, 0.f, 0.f};
  const size_t wdbase = ((size_t)e * D_MODEL + n0) * D_FFN;
  for (int k0 = 0; k0 < D_FFN; k0 += 64) {
    #pragma unroll
    for (int r = 0; r < 4; ++r) {
      int idx = tid + r * 256;
      int row = idx >> 3;
      int c8  = (idx & 7) * 8;
      const ushort* src = H + (size_t)(row_base + row) * D_FFN + k0 + c8;
      *(uint4*)(&As[row][c8]) = *(const uint4*)src;
    }
    #pragma unroll
    for (int r = 0; r < 8; ++r) {
      int idx = tid + r * 256;
      int row = idx >> 4;
      int c4  = (idx & 15) * 4;
      const float4 d = *(const float4*)(wd + wdbase + (size_t)row * D_FFN + k0 + c4);
      ushort4 db; db.x = f2bf(d.x); db.y = f2bf(d.y); db.z = f2bf(d.z); db.w = f2bf(d.w);
      *(ushort4*)(&Bd[row][c4]) = db;
    }
    __syncthreads();
    #pragma unroll
    for (int kk = 0; kk < 64; kk += 32) {
      bf16x8 af[4], bdf[4];
      #pragma unroll
      for (int mi = 0; mi < 4; ++mi)
        af[mi] = *(const bf16x8*)(&As[wm + mi * 16 + lrow][kk + lk]);
      #pragma unroll
      for (int ni = 0; ni < 4; ++ni)
        bdf[ni] = *(const bf16x8*)(&Bd[wn + ni * 16 + lrow][kk + lk]);
      #pragma unroll
      for (int mi = 0; mi < 4; ++mi)
        #pragma unroll
        for (int ni = 0; ni < 4; ++ni)
          acc[mi][ni] = __builtin_amdgcn_mfma_f32_16x16x32_bf16(af[mi], bdf[ni], acc[mi][ni], 0, 0, 0);
    }
    __syncthreads();
  }
  #pragma unroll
  for (int mi = 0; mi < 4; ++mi)
    #pragma unroll
    for (int ni = 0; ni < 4; ++ni)
      #pragma unroll
      for (int r4 = 0; r4 < 4; ++r4) {
        int m = wm + mi * 16 + (lane >> 4) * 4 + r4;
        if (m0 + m < Ne) {
          int n = wn + ni * 16 + (lane & 15);
          float v = acc[mi][ni][r4] * wt_s[m];
          atomicAdd(&out[(size_t)tok_s[m] * D_MODEL + (n0 + n)], v);
        }
      }
}

__global__ __launch_bounds__(256) void ln_kernel(
    float* __restrict__ out, const float* __restrict__ gamma,
    const float* __restrict__ beta)
{
  const int row = blockIdx.x;
  const int t   = threadIdx.x;
  float* rp = out + (size_t)row * D_MODEL;
  float4 v = ((const float4*)rp)[t];
  float s = v.x + v.y + v.z + v.w;
  #pragma unroll
  for (int o = 32; o > 0; o >>= 1) s += __shfl_xor(s, o, 64);
  __shared__ float red[4];
  const int wave = t >> 6, lane = t & 63;
  if (lane == 0) red[wave] = s;
  __syncthreads();
  float mean = (red[0] + red[1] + red[2] + red[3]) * (1.f / D_MODEL);
  float dx = v.x - mean, dy = v.y - mean, dz = v.z - mean, dw = v.w - mean;
  float ss = dx * dx + dy * dy + dz * dz + dw * dw;
  #pragma unroll
  for (int o = 32; o > 0; o >>= 1) ss += __shfl_xor(ss, o, 64);
  __syncthreads();
  if (lane == 0) red[wave] = ss;
  __syncthreads();
  float var = (red[0] + red[1] + red[2] + red[3]) * (1.f / D_MODEL);
  float rs  = rsqrtf(var + 1e-5f);
  float4 g = ((const float4*)gamma)[t];
  float4 b = ((const float4*)beta)[t];
  float4 o4;
  o4.x = dx * rs * g.x + b.x;
  o4.y = dy * rs * g.y + b.y;
  o4.z = dz * rs * g.z + b.z;
  o4.w = dw * rs * g.w + b.w;
  ((float4*)rp)[t] = o4;
}

// ======================= Launch =============================================
extern "C" void kernel_launch(void* const* d_in, const int* in_sizes, int n_in,
                              void* d_out, int out_size, void* d_ws, size_t ws_size,
                              hipStream_t stream) {
  const float* x        = (const float*)d_in[0];
  const float* w_router = (const float*)d_in[1];
  const float* w_gate   = (const float*)d_in[2];
  const float* w_up     = (const float*)d_in[3];
  const float* w_down   = (const float*)d_in[4];
  const float* ln_gamma = (const float*)d_in[5];
  const float* ln_beta  = (const float*)d_in[6];
  float* out = (float*)d_out;
  char* ws = (char*)d_ws;

  const size_t META = 262144;
  const size_t NEED = META + 3 * (size_t)W_ELEM * 2
                      + (size_t)TOKENS * D_MODEL * 2
                      + (size_t)ROWS_PAD * D_FFN * 2;   // ~143.4 MB

  if (ws_size >= NEED) {
    int*   counts   = (int*)ws;
    int*   tok_list = (int*)(ws + 4096);
    int*   slots    = (int*)(ws + 4096 + 131072);
    float* wts      = (float*)(ws + 4096 + 131072 + 32768);
    int*   eids     = (int*)(ws + 4096 + 131072 + 32768 + 32768);
    ushort* WgB = (ushort*)(ws + META);
    ushort* WuB = WgB + W_ELEM;
    ushort* WdB = WuB + W_ELEM;
    ushort* xb  = WdB + W_ELEM;
    ushort* H   = xb + (size_t)TOKENS * D_MODEL;
    ushort* Y   = WgB;   // alias: WgB/WuB dead after gateup3

    router_a_kernel<<<TOKENS / 4, 256, 0, stream>>>(x, w_router, xb, eids, wts);
    build_lists_kernel<<<N_EXP, 1024, 0, stream>>>(eids, counts, tok_list, slots);
    convert3_kernel<<<3 * 8192, 256, 0, stream>>>(w_gate, w_up, w_down, WgB);
    gateup3_kernel<<<dim3(D_FFN / 64, 32, N_EXP), 256, 0, stream>>>(
        xb, WgB, WuB, counts, tok_list, H);
    down3_kernel<<<dim3(D_MODEL / 64, 32, N_EXP), 256, 0, stream>>>(
        H, WdB, counts, Y);
    combine_ln3_kernel<<<TOKENS, 256, 0, stream>>>(Y, slots, wts, counts,
                                                   ln_gamma, ln_beta, out);
  } else {
    // round-1 fallback
    int*   counts   = (int*)ws;
    int*   offsets  = counts + 8;
    int*   tok_list = (int*)(ws + 256);
    float* wt_list  = (float*)(ws + 256 + LISTCAP * N_EXP * 4);
    ushort* xb      = (ushort*)(ws + 256 + LISTCAP * N_EXP * 8);
    ushort* H       = xb + (size_t)TOKENS * D_MODEL;

    hipMemsetAsync(counts, 0, 64, stream);
    hipMemsetAsync(out, 0, (size_t)TOKENS * D_MODEL * sizeof(float), stream);
    router_kernel<<<TOKENS, 64, 0, stream>>>(x, w_router, xb, counts, tok_list, wt_list);
    prefix_kernel<<<1, 64, 0, stream>>>(counts, offsets);
    gateup_kernel<<<dim3(D_FFN / 128, 32, N_EXP), 256, 0, stream>>>(
        xb, w_gate, w_up, counts, offsets, tok_list, H);
    down_kernel<<<dim3(D_MODEL / 128, 32, N_EXP), 256, 0, stream>>>(
        H, w_down, counts, offsets, tok_list, wt_list, out);
    ln_kernel<<<TOKENS, 256, 0, stream>>>(out, ln_gamma, ln_beta);
  }
}

// Round 4
// 372.361 us; speedup vs baseline: 1.2769x; 1.0690x over previous
//
#include <hip/hip_runtime.h>

// MoE layer: router top-2 + per-expert SwiGLU FFN + weighted combine + LayerNorm.
// Tokens=4096, D_MODEL=1024, D_FFN=2048, E=8, TOPK=2. fp32 I/O, bf16 MFMA inside.
//
// R3: (a) revert down3 to R0's 128x128 (R2's 128x64 retile cost ~20us: doubled
// A-panel re-reads + per-block overhead); (b) merge router_a + convert3 into
// one dispatch (independent work) -> 5 dispatches, tests whether the ~160us
// wall-vs-kernel-sum gap is per-dispatch overhead.
//
// Fast path: [router+convert] -> build_lists -> gateup3 (128x64) ->
// down3 (128x128) -> combine+LN. Fallback: round-1 pipeline.

#define D_MODEL 1024
#define D_FFN   2048
#define N_EXP   8
#define TOKENS  4096
#define LISTCAP 4096
#define ROWS_PAD 8320
#define W_ELEM  16777216u   // N_EXP * D_FFN * D_MODEL

typedef __bf16 bf16x8 __attribute__((ext_vector_type(8)));
typedef float  f32x4  __attribute__((ext_vector_type(4)));

__device__ __forceinline__ ushort f2bf(float f) {
  union { float f; unsigned u; } v; v.f = f;
  unsigned u = v.u;
  u += 0x7fffu + ((u >> 16) & 1u);   // round-to-nearest-even
  return (ushort)(u >> 16);
}
__device__ __forceinline__ float bf2f(ushort h) {
  union { unsigned u; float f; } v; v.u = ((unsigned)h) << 16; return v.f;
}
__device__ __forceinline__ void gl2lds16(const ushort* g, ushort* l) {
  __builtin_amdgcn_global_load_lds(
      (const __attribute__((address_space(1))) unsigned int*)g,
      (__attribute__((address_space(3))) unsigned int*)l, 16, 0, 0);
}

// ======================= FAST PATH ==========================================

// Merged: blocks [0,1024) = per-token router (logits, top-2 softmax, x->xb).
//         blocks [1024, 25600) = fp32->bf16 convert of wg|wu|wd (8192 each).
// The two halves are data-independent; merging saves a dispatch and overlaps
// the compute-light router with the BW-bound convert.
__global__ __launch_bounds__(256) void router_convert_kernel(
    const float* __restrict__ x, const float* __restrict__ wr,
    const float* __restrict__ wg, const float* __restrict__ wu,
    const float* __restrict__ wd,
    ushort* __restrict__ xb, int* __restrict__ eids, float* __restrict__ wts,
    ushort* __restrict__ dstBase)
{
  if (blockIdx.x < TOKENS / 4) {
    // ---- router path ----
    const int token = blockIdx.x * 4 + (threadIdx.x >> 6);
    const int lane  = threadIdx.x & 63;
    const float* xr = x + (size_t)token * D_MODEL + lane * 16;

    float xv[16];
    #pragma unroll
    for (int j = 0; j < 16; ++j) xv[j] = xr[j];

    ushort* xbr = xb + (size_t)token * D_MODEL + lane * 16;
    #pragma unroll
    for (int half = 0; half < 2; ++half) {
      ushort u8[8];
      #pragma unroll
      for (int j = 0; j < 8; ++j) u8[j] = f2bf(xv[half * 8 + j]);
      *(uint4*)(xbr + half * 8) = *(uint4*)u8;
    }

    float logit[N_EXP];
    #pragma unroll
    for (int e = 0; e < N_EXP; ++e) {
      const float* w = wr + e * D_MODEL + lane * 16;
      float p = 0.f;
      #pragma unroll
      for (int j = 0; j < 16; ++j) p += xv[j] * w[j];
      #pragma unroll
      for (int o = 32; o > 0; o >>= 1) p += __shfl_xor(p, o, 64);
      logit[e] = p;
    }

    if (lane == 0) {
      float v0 = -1e30f, v1 = -1e30f; int i0 = 0, i1 = 0;
      #pragma unroll
      for (int e = 0; e < N_EXP; ++e) {
        float v = logit[e];
        if (v > v0)      { v1 = v0; i1 = i0; v0 = v; i0 = e; }
        else if (v > v1) { v1 = v; i1 = e; }
      }
      float t  = expf(v1 - v0);         // stable 2-way softmax
      eids[token] = i0 | (i1 << 8);
      wts[token * 2]     = 1.f / (1.f + t);
      wts[token * 2 + 1] = t   / (1.f + t);
    }
  } else {
    // ---- convert path ----
    const int cid = blockIdx.x - TOKENS / 4;
    const int arr = cid >> 13;              // 8192 blocks per array
    const float* src = (arr == 0) ? wg : (arr == 1) ? wu : wd;
    ushort* dst = dstBase + (size_t)arr * W_ELEM;
    const size_t base = (((size_t)(cid & 8191)) * 256 + threadIdx.x) * 8;
    float4 a = *(const float4*)(src + base);
    float4 b = *(const float4*)(src + base + 4);
    ushort u8[8] = {f2bf(a.x), f2bf(a.y), f2bf(a.z), f2bf(a.w),
                    f2bf(b.x), f2bf(b.y), f2bf(b.z), f2bf(b.w)};
    *(uint4*)(dst + base) = *(uint4*)u8;
  }
}

// Phase B: one block per expert. Block-wide exclusive scan assigns positions.
__global__ __launch_bounds__(1024) void build_lists_kernel(
    const int* __restrict__ eids, int* __restrict__ counts,
    int* __restrict__ tok_list, int* __restrict__ slots)
{
  const int e = blockIdx.x;
  const int t = threadIdx.x;

  int my_k[4];
  int c = 0;
  #pragma unroll
  for (int i = 0; i < 4; ++i) {
    int tok = t + i * 1024;
    int p  = eids[tok];
    int e0 = p & 0xff, e1 = (p >> 8) & 0xff;
    my_k[i] = (e0 == e) ? 0 : (e1 == e) ? 1 : -1;
    c += (my_k[i] >= 0) ? 1 : 0;
  }

  const int wave = t >> 6, lane = t & 63;
  int v = c;
  #pragma unroll
  for (int o = 1; o < 64; o <<= 1) {
    int n = __shfl_up(v, o, 64);
    if (lane >= o) v += n;
  }

  __shared__ int wsum[16];
  __shared__ int wbase[16];
  if (lane == 63) wsum[wave] = v;
  __syncthreads();
  if (t == 0) {
    int s = 0;
    #pragma unroll
    for (int w = 0; w < 16; ++w) { wbase[w] = s; s += wsum[w]; }
    counts[e] = s;
  }
  __syncthreads();

  int pos = wbase[wave] + v - c;   // exclusive base for this thread
  #pragma unroll
  for (int i = 0; i < 4; ++i) {
    int tok = t + i * 1024;
    if (my_k[i] >= 0) {
      tok_list[e * LISTCAP + pos] = tok;
      slots[tok * 2 + my_k[i]] = e * LISTCAP + pos;
      pos++;
    }
  }
}

// Gate+Up grouped GEMM + SwiGLU -> H (bf16).
// 128(M)x64(N) tile, BK=64, indirect A via tok_list, global_load_lds + XOR swizzle.
__global__ __launch_bounds__(256, 3) void gateup3_kernel(
    const ushort* __restrict__ xb, const ushort* __restrict__ WgB,
    const ushort* __restrict__ WuB, const int* __restrict__ counts,
    const int* __restrict__ tok_list, ushort* __restrict__ H)
{
  const int e  = blockIdx.z;
  const int Ne = counts[e];
  const int m0 = blockIdx.y * 128;
  if (m0 >= Ne) return;
  const int n0 = blockIdx.x * 64;

  int rowoff = 0;
  for (int j = 0; j < e; ++j) rowoff += counts[j];

  __shared__ ushort As[128 * 64];
  __shared__ ushort Bg[64 * 64];
  __shared__ ushort Bu[64 * 64];
  __shared__ int tok_s[128];

  const int tid = threadIdx.x;
  if (tid < 128) {
    int i = m0 + tid;
    tok_s[tid] = tok_list[e * LISTCAP + (i < Ne ? i : Ne - 1)];
  }
  __syncthreads();

  const int wave = tid >> 6;
  const int lane = tid & 63;
  const int rsub = lane >> 3;
  const int cchk = lane & 7;
  const int co   = (cchk ^ rsub) << 3;    // r&7 == rsub for all staged rows

  const ushort* aSrc[4];
  #pragma unroll
  for (int i = 0; i < 4; ++i)
    aSrc[i] = xb + (size_t)tok_s[wave * 32 + i * 8 + rsub] * D_MODEL + co;
  const ushort* gS = WgB + ((size_t)e * D_FFN + n0 + wave * 16 + rsub) * D_MODEL + co;
  const ushort* uS = WuB + ((size_t)e * D_FFN + n0 + wave * 16 + rsub) * D_MODEL + co;
  ushort* aD = &As[(wave * 32) * 64];
  ushort* gD = &Bg[(wave * 16) * 64];
  ushort* uD = &Bu[(wave * 16) * 64];

  const int wm   = (wave >> 1) * 64;
  const int wn   = (wave & 1) * 32;
  const int lrow = lane & 15;
  const int lq   = lane >> 4;

  f32x4 accg[4][2], accu[4][2];
  #pragma unroll
  for (int i = 0; i < 4; ++i)
    #pragma unroll
    for (int j = 0; j < 2; ++j) {
      accg[i][j] = f32x4{0.f, 0.f, 0.f, 0.f};
      accu[i][j] = f32x4{0.f, 0.f, 0.f, 0.f};
    }

  for (int k0 = 0; k0 < D_MODEL; k0 += 64) {
    #pragma unroll
    for (int i = 0; i < 4; ++i) {
      gl2lds16(aSrc[i], aD + i * 8 * 64);
      aSrc[i] += 64;
    }
    #pragma unroll
    for (int i = 0; i < 2; ++i) {
      gl2lds16(gS + (size_t)i * 8 * D_MODEL, gD + i * 8 * 64);
      gl2lds16(uS + (size_t)i * 8 * D_MODEL, uD + i * 8 * 64);
    }
    gS += 64; uS += 64;
    __syncthreads();

    #pragma unroll
    for (int kk = 0; kk < 2; ++kk) {
      const int c = kk * 4 + lq;
      bf16x8 af[4], bgf[2], buf[2];
      #pragma unroll
      for (int mi = 0; mi < 4; ++mi) {
        int r = wm + mi * 16 + lrow;
        af[mi] = *(const bf16x8*)&As[r * 64 + ((c ^ (r & 7)) << 3)];
      }
      #pragma unroll
      for (int ni = 0; ni < 2; ++ni) {
        int r = wn + ni * 16 + lrow;
        int off = r * 64 + ((c ^ (r & 7)) << 3);
        bgf[ni] = *(const bf16x8*)&Bg[off];
        buf[ni] = *(const bf16x8*)&Bu[off];
      }
      #pragma unroll
      for (int mi = 0; mi < 4; ++mi)
        #pragma unroll
        for (int ni = 0; ni < 2; ++ni) {
          accg[mi][ni] = __builtin_amdgcn_mfma_f32_16x16x32_bf16(af[mi], bgf[ni], accg[mi][ni], 0, 0, 0);
          accu[mi][ni] = __builtin_amdgcn_mfma_f32_16x16x32_bf16(af[mi], buf[ni], accu[mi][ni], 0, 0, 0);
        }
    }
    __syncthreads();
  }

  const int rowbase = rowoff + m0;
  #pragma unroll
  for (int mi = 0; mi < 4; ++mi)
    #pragma unroll
    for (int r4 = 0; r4 < 4; ++r4) {
      int m = wm + mi * 16 + lq * 4 + r4;
      if (m0 + m < Ne) {
        ushort* hr = H + (size_t)(rowbase + m) * D_FFN + n0 + wn + lrow;
        #pragma unroll
        for (int ni = 0; ni < 2; ++ni) {
          float g = accg[mi][ni][r4];
          float u = accu[mi][ni][r4];
          float h = g / (1.f + __expf(-g)) * u;
          hr[ni * 16] = f2bf(h);
        }
      }
    }
}

// Down grouped GEMM -> Y rows (bf16, unweighted). 128x128 tile, BK=64. (R0 config)
__global__ __launch_bounds__(256, 3) void down3_kernel(
    const ushort* __restrict__ H, const ushort* __restrict__ WdB,
    const int* __restrict__ counts, ushort* __restrict__ Y)
{
  const int e  = blockIdx.z;
  const int Ne = counts[e];
  const int m0 = blockIdx.y * 128;
  if (m0 >= Ne) return;
  const int n0 = blockIdx.x * 128;

  int rowoff = 0;
  for (int j = 0; j < e; ++j) rowoff += counts[j];
  const int rowbase = rowoff + m0;

  __shared__ ushort As[128 * 64];
  __shared__ ushort Bd[128 * 64];

  const int tid  = threadIdx.x;
  const int wave = tid >> 6;
  const int lane = tid & 63;
  const int rsub = lane >> 3;
  const int cchk = lane & 7;
  const int co   = (cchk ^ rsub) << 3;

  const ushort* aS = H   + (size_t)(rowbase + wave * 32 + rsub) * D_FFN + co;
  const ushort* bS = WdB + (size_t)(e * D_MODEL + n0 + wave * 32 + rsub) * D_FFN + co;
  ushort* aD = &As[(wave * 32) * 64];
  ushort* bD = &Bd[(wave * 32) * 64];

  const int wm   = (wave >> 1) * 64;
  const int wn   = (wave & 1) * 64;
  const int lrow = lane & 15;
  const int lq   = lane >> 4;

  f32x4 acc[4][4];
  #pragma unroll
  for (int i = 0; i < 4; ++i)
    #pragma unroll
    for (int j = 0; j < 4; ++j) acc[i][j] = f32x4{0.f, 0.f, 0.f, 0.f};

  for (int k0 = 0; k0 < D_FFN; k0 += 64) {
    #pragma unroll
    for (int i = 0; i < 4; ++i) {
      gl2lds16(aS + (size_t)i * 8 * D_FFN, aD + i * 8 * 64);
      gl2lds16(bS + (size_t)i * 8 * D_FFN, bD + i * 8 * 64);
    }
    aS += 64; bS += 64;
    __syncthreads();

    #pragma unroll
    for (int kk = 0; kk < 2; ++kk) {
      const int c = kk * 4 + lq;
      bf16x8 af[4], bf[4];
      #pragma unroll
      for (int mi = 0; mi < 4; ++mi) {
        int r = wm + mi * 16 + lrow;
        af[mi] = *(const bf16x8*)&As[r * 64 + ((c ^ (r & 7)) << 3)];
      }
      #pragma unroll
      for (int ni = 0; ni < 4; ++ni) {
        int r = wn + ni * 16 + lrow;
        bf[ni] = *(const bf16x8*)&Bd[r * 64 + ((c ^ (r & 7)) << 3)];
      }
      #pragma unroll
      for (int mi = 0; mi < 4; ++mi)
        #pragma unroll
        for (int ni = 0; ni < 4; ++ni)
          acc[mi][ni] = __builtin_amdgcn_mfma_f32_16x16x32_bf16(af[mi], bf[ni], acc[mi][ni], 0, 0, 0);
    }
    __syncthreads();
  }

  #pragma unroll
  for (int mi = 0; mi < 4; ++mi)
    #pragma unroll
    for (int r4 = 0; r4 < 4; ++r4) {
      int m = wm + mi * 16 + lq * 4 + r4;
      if (m0 + m < Ne) {
        ushort* yr = Y + (size_t)(rowbase + m) * D_MODEL + n0 + wn + lrow;
        #pragma unroll
        for (int ni = 0; ni < 4; ++ni)
          yr[ni * 16] = f2bf(acc[mi][ni][r4]);
      }
    }
}

// Combine the 2 expert rows per token + LayerNorm -> out (fp32).
__global__ __launch_bounds__(256) void combine_ln3_kernel(
    const ushort* __restrict__ Y, const int* __restrict__ slots,
    const float* __restrict__ wts, const int* __restrict__ counts,
    const float* __restrict__ gamma, const float* __restrict__ beta,
    float* __restrict__ out)
{
  const int token = blockIdx.x;
  const int t = threadIdx.x;

  __shared__ int offs_s[N_EXP];
  if (t == 0) {
    int s = 0;
    #pragma unroll
    for (int j = 0; j < N_EXP; ++j) { offs_s[j] = s; s += counts[j]; }
  }
  __syncthreads();

  const int s0 = slots[token * 2], s1 = slots[token * 2 + 1];
  const float w0 = wts[token * 2], w1 = wts[token * 2 + 1];
  const int r0 = offs_s[s0 >> 12] + (s0 & (LISTCAP - 1));
  const int r1 = offs_s[s1 >> 12] + (s1 & (LISTCAP - 1));

  ushort4 a = *(const ushort4*)(Y + (size_t)r0 * D_MODEL + t * 4);
  ushort4 b = *(const ushort4*)(Y + (size_t)r1 * D_MODEL + t * 4);
  float4 v;
  v.x = w0 * bf2f(a.x) + w1 * bf2f(b.x);
  v.y = w0 * bf2f(a.y) + w1 * bf2f(b.y);
  v.z = w0 * bf2f(a.z) + w1 * bf2f(b.z);
  v.w = w0 * bf2f(a.w) + w1 * bf2f(b.w);

  float s = v.x + v.y + v.z + v.w;
  #pragma unroll
  for (int o = 32; o > 0; o >>= 1) s += __shfl_xor(s, o, 64);
  __shared__ float red[4];
  const int wave = t >> 6, lane = t & 63;
  if (lane == 0) red[wave] = s;
  __syncthreads();
  float mean = (red[0] + red[1] + red[2] + red[3]) * (1.f / D_MODEL);

  float dx = v.x - mean, dy = v.y - mean, dz = v.z - mean, dw = v.w - mean;
  float ss = dx * dx + dy * dy + dz * dz + dw * dw;
  #pragma unroll
  for (int o = 32; o > 0; o >>= 1) ss += __shfl_xor(ss, o, 64);
  __syncthreads();
  if (lane == 0) red[wave] = ss;
  __syncthreads();
  float var = (red[0] + red[1] + red[2] + red[3]) * (1.f / D_MODEL);
  float rs  = rsqrtf(var + 1e-5f);

  float4 g = ((const float4*)gamma)[t];
  float4 bb = ((const float4*)beta)[t];
  float4 o4;
  o4.x = dx * rs * g.x + bb.x;
  o4.y = dy * rs * g.y + bb.y;
  o4.z = dz * rs * g.z + bb.z;
  o4.w = dw * rs * g.w + bb.w;
  ((float4*)(out + (size_t)token * D_MODEL))[t] = o4;
}

// ======================= FALLBACK (round-1, known-correct) ==================
__global__ __launch_bounds__(64) void router_kernel(
    const float* __restrict__ x, const float* __restrict__ wr,
    ushort* __restrict__ xb, int* __restrict__ counts,
    int* __restrict__ tok_list, float* __restrict__ wt_list)
{
  const int token = blockIdx.x;
  const int lane  = threadIdx.x;
  const float* xr = x + (size_t)token * D_MODEL;
  float xv[16];
  #pragma unroll
  for (int j = 0; j < 16; ++j) xv[j] = xr[j * 64 + lane];
  ushort* xbr = xb + (size_t)token * D_MODEL;
  #pragma unroll
  for (int j = 0; j < 16; ++j) xbr[j * 64 + lane] = f2bf(xv[j]);
  float logit[N_EXP];
  #pragma unroll
  for (int e = 0; e < N_EXP; ++e) {
    const float* w = wr + e * D_MODEL;
    float p = 0.f;
    #pragma unroll
    for (int j = 0; j < 16; ++j) p += xv[j] * w[j * 64 + lane];
    #pragma unroll
    for (int o = 32; o > 0; o >>= 1) p += __shfl_xor(p, o, 64);
    logit[e] = p;
  }
  if (lane == 0) {
    float v0 = -1e30f, v1 = -1e30f; int i0 = 0, i1 = 0;
    #pragma unroll
    for (int e = 0; e < N_EXP; ++e) {
      float v = logit[e];
      if (v > v0)      { v1 = v0; i1 = i0; v0 = v; i0 = e; }
      else if (v > v1) { v1 = v; i1 = e; }
    }
    float t  = expf(v1 - v0);
    float w0 = 1.f / (1.f + t);
    float w1 = t   / (1.f + t);
    int p0 = atomicAdd(&counts[i0], 1);
    tok_list[i0 * LISTCAP + p0] = token;
    wt_list[i0 * LISTCAP + p0] = w0;
    int p1 = atomicAdd(&counts[i1], 1);
    tok_list[i1 * LISTCAP + p1] = token;
    wt_list[i1 * LISTCAP + p1] = w1;
  }
}

__global__ void prefix_kernel(const int* __restrict__ counts, int* __restrict__ offsets)
{
  if (threadIdx.x == 0 && blockIdx.x == 0) {
    int s = 0;
    for (int e = 0; e < N_EXP; ++e) { offsets[e] = s; s += counts[e]; }
  }
}

__global__ __launch_bounds__(256, 2) void gateup_kernel(
    const ushort* __restrict__ xb, const float* __restrict__ wg,
    const float* __restrict__ wu, const int* __restrict__ counts,
    const int* __restrict__ offsets, const int* __restrict__ tok_list,
    ushort* __restrict__ H)
{
  const int e  = blockIdx.z;
  const int Ne = counts[e];
  const int m0 = blockIdx.y * 128;
  if (m0 >= Ne) return;
  const int n0 = blockIdx.x * 128;
  __shared__ ushort As[128][80];
  __shared__ ushort Bg[128][80];
  __shared__ ushort Bu[128][80];
  __shared__ int tok_s[128];
  const int tid = threadIdx.x;
  if (tid < 128) {
    int i = m0 + tid;
    tok_s[tid] = tok_list[e * LISTCAP + (i < Ne ? i : 0)];
  }
  __syncthreads();
  const int wave = tid >> 6;
  const int lane = tid & 63;
  const int wm   = (wave >> 1) * 64;
  const int wn   = (wave & 1) * 64;
  const int lrow = lane & 15;
  const int lk   = (lane >> 4) * 8;
  f32x4 accg[4][4], accu[4][4];
  #pragma unroll
  for (int i = 0; i < 4; ++i)
    #pragma unroll
    for (int j = 0; j < 4; ++j) {
      accg[i][j] = f32x4{0.f, 0.f, 0.f, 0.f};
      accu[i][j] = f32x4{0.f, 0.f, 0.f, 0.f};
    }
  const size_t wbase = ((size_t)e * D_FFN + n0) * D_MODEL;
  for (int k0 = 0; k0 < D_MODEL; k0 += 64) {
    #pragma unroll
    for (int r = 0; r < 4; ++r) {
      int idx = tid + r * 256;
      int row = idx >> 3;
      int c8  = (idx & 7) * 8;
      const ushort* src = xb + (size_t)tok_s[row] * D_MODEL + k0 + c8;
      *(uint4*)(&As[row][c8]) = *(const uint4*)src;
    }
    #pragma unroll
    for (int r = 0; r < 8; ++r) {
      int idx = tid + r * 256;
      int row = idx >> 4;
      int c4  = (idx & 15) * 4;
      const size_t off = wbase + (size_t)row * D_MODEL + k0 + c4;
      const float4 g = *(const float4*)(wg + off);
      const float4 u = *(const float4*)(wu + off);
      ushort4 gb; gb.x = f2bf(g.x); gb.y = f2bf(g.y); gb.z = f2bf(g.z); gb.w = f2bf(g.w);
      ushort4 ub; ub.x = f2bf(u.x); ub.y = f2bf(u.y); ub.z = f2bf(u.z); ub.w = f2bf(u.w);
      *(ushort4*)(&Bg[row][c4]) = gb;
      *(ushort4*)(&Bu[row][c4]) = ub;
    }
    __syncthreads();
    #pragma unroll
    for (int kk = 0; kk < 64; kk += 32) {
      bf16x8 af[4], bgf[4], buf[4];
      #pragma unroll
      for (int mi = 0; mi < 4; ++mi)
        af[mi] = *(const bf16x8*)(&As[wm + mi * 16 + lrow][kk + lk]);
      #pragma unroll
      for (int ni = 0; ni < 4; ++ni) {
        bgf[ni] = *(const bf16x8*)(&Bg[wn + ni * 16 + lrow][kk + lk]);
        buf[ni] = *(const bf16x8*)(&Bu[wn + ni * 16 + lrow][kk + lk]);
      }
      #pragma unroll
      for (int mi = 0; mi < 4; ++mi)
        #pragma unroll
        for (int ni = 0; ni < 4; ++ni) {
          accg[mi][ni] = __builtin_amdgcn_mfma_f32_16x16x32_bf16(af[mi], bgf[ni], accg[mi][ni], 0, 0, 0);
          accu[mi][ni] = __builtin_amdgcn_mfma_f32_16x16x32_bf16(af[mi], buf[ni], accu[mi][ni], 0, 0, 0);
        }
    }
    __syncthreads();
  }
  const int row_base = offsets[e] + m0;
  #pragma unroll
  for (int mi = 0; mi < 4; ++mi)
    #pragma unroll
    for (int ni = 0; ni < 4; ++ni)
      #pragma unroll
      for (int r4 = 0; r4 < 4; ++r4) {
        int m = wm + mi * 16 + (lane >> 4) * 4 + r4;
        if (m0 + m < Ne) {
          int n = wn + ni * 16 + (lane & 15);
          float g = accg[mi][ni][r4];
          float u = accu[mi][ni][r4];
          float h = g / (1.f + __expf(-g)) * u;
          H[(size_t)(row_base + m) * D_FFN + (n0 + n)] = f2bf(h);
        }
      }
}

__global__ __launch_bounds__(256, 2) void down_kernel(
    const ushort* __restrict__ H, const float* __restrict__ wd,
    const int* __restrict__ counts, const int* __restrict__ offsets,
    const int* __restrict__ tok_list, const float* __restrict__ wt_list,
    float* __restrict__ out)
{
  const int e  = blockIdx.z;
  const int Ne = counts[e];
  const int m0 = blockIdx.y * 128;
  if (m0 >= Ne) return;
  const int n0 = blockIdx.x * 128;
  __shared__ ushort As[128][80];
  __shared__ ushort Bd[128][80];
  __shared__ int   tok_s[128];
  __shared__ float wt_s[128];
  const int tid = threadIdx.x;
  if (tid < 128) {
    int i  = m0 + tid;
    int ok = (i < Ne);
    tok_s[tid] = tok_list[e * LISTCAP + (ok ? i : 0)];
    wt_s[tid]  = ok ? wt_list[e * LISTCAP + i] : 0.f;
  }
  __syncthreads();
  const int wave = tid >> 6;
  const int lane = tid & 63;
  const int wm   = (wave >> 1) * 64;
  const int wn   = (wave & 1) * 64;
  const int lrow = lane & 15;
  const int lk   = (lane >> 4) * 8;
  const int row_base = offsets[e] + m0;
  f32x4 acc[4][4];
  #pragma unroll
  for (int i = 0; i < 4; ++i)
    #pragma unroll
    for (int j = 0; j < 4; ++j) acc[i][j] = f32x4{0.f, 0.f, 0.f, 0.f};
  const size_t wdbase = ((size_t)e * D_MODEL + n0) * D_FFN;
  for (int k0 = 0; k0 < D_FFN; k0 += 64) {
    #pragma unroll
    for (int r = 0; r < 4; ++r) {
      int idx = tid + r * 256;
      int row = idx >> 3;
      int c8  = (idx & 7) * 8;
      const ushort* src = H + (size_t)(row_base + row) * D_FFN + k0 + c8;
      *(uint4*)(&As[row][c8]) = *(const uint4*)src;
    }
    #pragma unroll
    for (int r = 0; r < 8; ++r) {
      int idx = tid + r * 256;
      int row = idx >> 4;
      int c4  = (idx & 15) * 4;
      const float4 d = *(const float4*)(wd + wdbase + (size_t)row * D_FFN + k0 + c4);
      ushort4 db; db.x = f2bf(d.x); db.y = f2bf(d.y); db.z = f2bf(d.z); db.w = f2bf(d.w);
      *(ushort4*)(&Bd[row][c4]) = db;
    }
    __syncthreads();
    #pragma unroll
    for (int kk = 0; kk < 64; kk += 32) {
      bf16x8 af[4], bdf[4];
      #pragma unroll
      for (int mi = 0; mi < 4; ++mi)
        af[mi] = *(const bf16x8*)(&As[wm + mi * 16 + lrow][kk + lk]);
      #pragma unroll
      for (int ni = 0; ni < 4; ++ni)
        bdf[ni] = *(const bf16x8*)(&Bd[wn + ni * 16 + lrow][kk + lk]);
      #pragma unroll
      for (int mi = 0; mi < 4; ++mi)
        #pragma unroll
        for (int ni = 0; ni < 4; ++ni)
          acc[mi][ni] = __builtin_amdgcn_mfma_f32_16x16x32_bf16(af[mi], bdf[ni], acc[mi][ni], 0, 0, 0);
    }
    __syncthreads();
  }
  #pragma unroll
  for (int mi = 0; mi < 4; ++mi)
    #pragma unroll
    for (int ni = 0; ni < 4; ++ni)
      #pragma unroll
      for (int r4 = 0; r4 < 4; ++r4) {
        int m = wm + mi * 16 + (lane >> 4) * 4 + r4;
        if (m0 + m < Ne) {
          int n = wn + ni * 16 + (lane & 15);
          float v = acc[mi][ni][r4] * wt_s[m];
          atomicAdd(&out[(size_t)tok_s[m] * D_MODEL + (n0 + n)], v);
        }
      }
}

__global__ __launch_bounds__(256) void ln_kernel(
    float* __restrict__ out, const float* __restrict__ gamma,
    const float* __restrict__ beta)
{
  const int row = blockIdx.x;
  const int t   = threadIdx.x;
  float* rp = out + (size_t)row * D_MODEL;
  float4 v = ((const float4*)rp)[t];
  float s = v.x + v.y + v.z + v.w;
  #pragma unroll
  for (int o = 32; o > 0; o >>= 1) s += __shfl_xor(s, o, 64);
  __shared__ float red[4];
  const int wave = t >> 6, lane = t & 63;
  if (lane == 0) red[wave] = s;
  __syncthreads();
  float mean = (red[0] + red[1] + red[2] + red[3]) * (1.f / D_MODEL);
  float dx = v.x - mean, dy = v.y - mean, dz = v.z - mean, dw = v.w - mean;
  float ss = dx * dx + dy * dy + dz * dz + dw * dw;
  #pragma unroll
  for (int o = 32; o > 0; o >>= 1) ss += __shfl_xor(ss, o, 64);
  __syncthreads();
  if (lane == 0) red[wave] = ss;
  __syncthreads();
  float var = (red[0] + red[1] + red[2] + red[3]) * (1.f / D_MODEL);
  float rs  = rsqrtf(var + 1e-5f);
  float4 g = ((const float4*)gamma)[t];
  float4 b = ((const float4*)beta)[t];
  float4 o4;
  o4.x = dx * rs * g.x + b.x;
  o4.y = dy * rs * g.y + b.y;
  o4.z = dz * rs * g.z + b.z;
  o4.w = dw * rs * g.w + b.w;
  ((float4*)rp)[t] = o4;
}

// ======================= Launch =============================================
extern "C" void kernel_launch(void* const* d_in, const int* in_sizes, int n_in,
                              void* d_out, int out_size, void* d_ws, size_t ws_size,
                              hipStream_t stream) {
  const float* x        = (const float*)d_in[0];
  const float* w_router = (const float*)d_in[1];
  const float* w_gate   = (const float*)d_in[2];
  const float* w_up     = (const float*)d_in[3];
  const float* w_down   = (const float*)d_in[4];
  const float* ln_gamma = (const float*)d_in[5];
  const float* ln_beta  = (const float*)d_in[6];
  float* out = (float*)d_out;
  char* ws = (char*)d_ws;

  const size_t META = 262144;
  const size_t NEED = META + 3 * (size_t)W_ELEM * 2
                      + (size_t)TOKENS * D_MODEL * 2
                      + (size_t)ROWS_PAD * D_FFN * 2;   // ~143.4 MB

  if (ws_size >= NEED) {
    int*   counts   = (int*)ws;
    int*   tok_list = (int*)(ws + 4096);
    int*   slots    = (int*)(ws + 4096 + 131072);
    float* wts      = (float*)(ws + 4096 + 131072 + 32768);
    int*   eids     = (int*)(ws + 4096 + 131072 + 32768 + 32768);
    ushort* WgB = (ushort*)(ws + META);
    ushort* WuB = WgB + W_ELEM;
    ushort* WdB = WuB + W_ELEM;
    ushort* xb  = WdB + W_ELEM;
    ushort* H   = xb + (size_t)TOKENS * D_MODEL;
    ushort* Y   = WgB;   // alias: WgB/WuB dead after gateup3

    router_convert_kernel<<<TOKENS / 4 + 3 * 8192, 256, 0, stream>>>(
        x, w_router, w_gate, w_up, w_down, xb, eids, wts, WgB);
    build_lists_kernel<<<N_EXP, 1024, 0, stream>>>(eids, counts, tok_list, slots);
    gateup3_kernel<<<dim3(D_FFN / 64, 32, N_EXP), 256, 0, stream>>>(
        xb, WgB, WuB, counts, tok_list, H);
    down3_kernel<<<dim3(D_MODEL / 128, 32, N_EXP), 256, 0, stream>>>(
        H, WdB, counts, Y);
    combine_ln3_kernel<<<TOKENS, 256, 0, stream>>>(Y, slots, wts, counts,
                                                   ln_gamma, ln_beta, out);
  } else {
    // round-1 fallback
    int*   counts   = (int*)ws;
    int*   offsets  = counts + 8;
    int*   tok_list = (int*)(ws + 256);
    float* wt_list  = (float*)(ws + 256 + LISTCAP * N_EXP * 4);
    ushort* xb      = (ushort*)(ws + 256 + LISTCAP * N_EXP * 8);
    ushort* H       = xb + (size_t)TOKENS * D_MODEL;

    hipMemsetAsync(counts, 0, 64, stream);
    hipMemsetAsync(out, 0, (size_t)TOKENS * D_MODEL * sizeof(float), stream);
    router_kernel<<<TOKENS, 64, 0, stream>>>(x, w_router, xb, counts, tok_list, wt_list);
    prefix_kernel<<<1, 64, 0, stream>>>(counts, offsets);
    gateup_kernel<<<dim3(D_FFN / 128, 32, N_EXP), 256, 0, stream>>>(
        xb, w_gate, w_up, counts, offsets, tok_list, H);
    down_kernel<<<dim3(D_MODEL / 128, 32, N_EXP), 256, 0, stream>>>(
        H, w_down, counts, offsets, tok_list, wt_list, out);
    ln_kernel<<<TOKENS, 256, 0, stream>>>(out, ln_gamma, ln_beta);
  }
}